// Round 5
// baseline (781.572 us; speedup 1.0000x reference)
//
#include <hip/hip_runtime.h>
#include <hip/hip_bf16.h>
#include <cstdint>
#include <cstddef>

#define LEAKY(x) ((x) > 0.f ? (x) : 0.2f * (x))

__device__ __forceinline__ float readlane_f(float v, int l) {
    return __int_as_float(__builtin_amdgcn_readlane(__float_as_int(v), l));
}
// round-to-nearest-even fp32 -> bf16 bits
__device__ __forceinline__ unsigned short f2bf(float f) {
    unsigned x = __float_as_uint(f);
    return (unsigned short)((x + 0x7fffu + ((x >> 16) & 1u)) >> 16);
}
__device__ __forceinline__ float bf_lo(unsigned u) { return __uint_as_float(u << 16); }
__device__ __forceinline__ float bf_hi(unsigned u) { return __uint_as_float(u & 0xffff0000u); }

// ---------------------------------------------------------------- CSR build
__global__ void hist_dst(const int* __restrict__ ei, int E, int* __restrict__ deg) {
    int e = blockIdx.x * 256 + threadIdx.x;
    if (e < E) atomicAdd(&deg[ei[E + e]], 1);
}

__global__ void scan_phase1(const int* __restrict__ deg, int n, int* __restrict__ bsum) {
    __shared__ int red[256];
    int t = threadIdx.x;
    int base = blockIdx.x * 2048;
    int s = 0;
#pragma unroll
    for (int i = 0; i < 8; ++i) {
        int idx = base + t * 8 + i;
        s += (idx < n) ? deg[idx] : 0;
    }
    red[t] = s;
    __syncthreads();
    for (int o = 128; o > 0; o >>= 1) {
        if (t < o) red[t] += red[t + o];
        __syncthreads();
    }
    if (t == 0) bsum[blockIdx.x] = red[0];
}

__global__ void scan_phase2(int* __restrict__ bsum, int nb, int* __restrict__ offsets, int n) {
    if (threadIdx.x == 0 && blockIdx.x == 0) {
        int run = 0;
        for (int i = 0; i < nb; ++i) {
            int v = bsum[i];
            bsum[i] = run;
            run += v;
        }
        offsets[n] = run;
    }
}

__global__ void scan_phase3(const int* __restrict__ deg, int n, const int* __restrict__ bsum,
                            int* __restrict__ out) {
    __shared__ int sh[256];
    int t = threadIdx.x;
    int base = blockIdx.x * 2048;
    int loc[8];
    int s = 0;
#pragma unroll
    for (int i = 0; i < 8; ++i) {
        int idx = base + t * 8 + i;
        loc[i] = (idx < n) ? deg[idx] : 0;
        s += loc[i];
    }
    sh[t] = s;
    __syncthreads();
    for (int o = 1; o < 256; o <<= 1) {
        int add = (t >= o) ? sh[t - o] : 0;
        __syncthreads();
        sh[t] += add;
        __syncthreads();
    }
    int excl = sh[t] - s + bsum[blockIdx.x];
#pragma unroll
    for (int i = 0; i < 8; ++i) {
        int idx = base + t * 8 + i;
        if (idx < n) out[idx] = excl;
        excl += loc[i];
    }
}

__global__ void scatter_csr(const int* __restrict__ ei, int E, int* __restrict__ cursor,
                            int* __restrict__ csr) {
    int e = blockIdx.x * 256 + threadIdx.x;
    if (e < E) {
        int d = ei[E + e];
        int s = ei[e];
        int pos = atomicAdd(&cursor[d], 1);
        csr[pos] = s;
    }
}

// ---------------------------------------------------------------- GEMM: W resident in LDS
// C[M,NOUT] = A[M,128] @ B[128,NOUT]. 4 waves/block, 4 rows/wave/iter,
// x broadcast via v_readlane, W read conflict-free from LDS. One barrier total.
template <int NOUT>
__global__ __launch_bounds__(256) void gemm_rl(const float* __restrict__ A,
                                               const float* __restrict__ B,
                                               float* __restrict__ C, int M) {
    __shared__ float Wl[128 * NOUT];
    const int tid = threadIdx.x;
    for (int i = tid * 4; i < 128 * NOUT; i += 1024)
        *(float4*)&Wl[i] = *(const float4*)&B[i];
    __syncthreads();

    const int lane = tid & 63;
    const int gw = blockIdx.x * 4 + (tid >> 6);
    const int stride = gridDim.x * 4 * 4;  // rows per sweep
    int rb = gw * 4;
    if (rb >= M) return;

    float xa[4], xb[4];
#pragma unroll
    for (int r = 0; r < 4; ++r) {
        int row = min(rb + r, M - 1);
        xa[r] = A[(size_t)row * 128 + lane];
        xb[r] = A[(size_t)row * 128 + 64 + lane];
    }

    while (true) {
        const int rn = rb + stride;
        const bool has_next = rn < M;
        float ya[4], yb[4];
        if (has_next) {
#pragma unroll
            for (int r = 0; r < 4; ++r) {
                int row = min(rn + r, M - 1);
                ya[r] = A[(size_t)row * 128 + lane];
                yb[r] = A[(size_t)row * 128 + 64 + lane];
            }
        }
        float acc0[4] = {0.f, 0.f, 0.f, 0.f};
        float acc1[4] = {0.f, 0.f, 0.f, 0.f};
#pragma unroll
        for (int k = 0; k < 128; ++k) {
            float w0 = Wl[k * NOUT + lane];
            float w1 = (NOUT == 128) ? Wl[k * NOUT + 64 + lane] : 0.f;
#pragma unroll
            for (int r = 0; r < 4; ++r) {
                float xk = readlane_f((k < 64) ? xa[r] : xb[r], k & 63);
                acc0[r] = fmaf(xk, w0, acc0[r]);
                if (NOUT == 128) acc1[r] = fmaf(xk, w1, acc1[r]);
            }
        }
#pragma unroll
        for (int r = 0; r < 4; ++r) {
            int row = rb + r;
            if (row < M) {
                C[(size_t)row * NOUT + lane] = acc0[r];
                if (NOUT == 128) C[(size_t)row * NOUT + 64 + lane] = acc1[r];
            }
        }
        if (!has_next) break;
#pragma unroll
        for (int r = 0; r < 4; ++r) { xa[r] = ya[r]; xb[r] = yb[r]; }
        rb = rn;
    }
}

// ---------------------------------------------------------------- attention scores (+ bf16 pack)
__global__ void att_scores_h2(const float* __restrict__ h, const float* __restrict__ att_src,
                              const float* __restrict__ att_dst, float* __restrict__ asrc,
                              float* __restrict__ adst, unsigned* __restrict__ hpk, int N) {
    int wid = (blockIdx.x * blockDim.x + threadIdx.x) >> 6;
    int lane = threadIdx.x & 63;
    if (wid >= N) return;
    const float* row = h + (size_t)wid * 128;
    float h0 = row[lane], h1 = row[64 + lane];
    hpk[(size_t)wid * 64 + lane] = (unsigned)f2bf(h0) | ((unsigned)f2bf(h1) << 16);
    float s0 = h0 * att_src[lane], s1 = h1 * att_src[64 + lane];
    float d0 = h0 * att_dst[lane], d1 = h1 * att_dst[64 + lane];
    for (int m = 32; m > 0; m >>= 1) {
        s0 += __shfl_xor(s0, m);
        s1 += __shfl_xor(s1, m);
        d0 += __shfl_xor(d0, m);
        d1 += __shfl_xor(d1, m);
    }
    if (lane == 0) {
        asrc[wid * 2] = s0; asrc[wid * 2 + 1] = s1;
        adst[wid * 2] = d0; adst[wid * 2 + 1] = d1;
    }
}

__global__ void att_scores_h1(const float* __restrict__ h, const float* __restrict__ att_src,
                              const float* __restrict__ att_dst, float* __restrict__ asrc,
                              float* __restrict__ adst, unsigned short* __restrict__ hb, int N) {
    int wid = (blockIdx.x * blockDim.x + threadIdx.x) >> 6;
    int lane = threadIdx.x & 63;
    if (wid >= N) return;
    float hv = h[(size_t)wid * 64 + lane];
    hb[(size_t)wid * 64 + lane] = f2bf(hv);
    float s = hv * att_src[lane];
    float d = hv * att_dst[lane];
    for (int m = 32; m > 0; m >>= 1) {
        s += __shfl_xor(s, m);
        d += __shfl_xor(d, m);
    }
    if (lane == 0) {
        asrc[wid] = s;
        adst[wid] = d;
    }
}

// ---------------------------------------------------------------- fused softmax+aggregate
// layer1: ONE wave per node, both heads from one packed uint gather.
__global__ void agg_layer1(const unsigned* __restrict__ hpk, const float* __restrict__ asrc,
                           const float* __restrict__ adst, const int* __restrict__ offs,
                           const int* __restrict__ csr, const float* __restrict__ bias,
                           float* __restrict__ out, int N) {
    int node = (blockIdx.x * blockDim.x + threadIdx.x) >> 6;
    int lane = threadIdx.x & 63;
    if (node >= N) return;
    int off = offs[node], end = offs[node + 1];
    float ad0 = adst[2 * node], ad1 = adst[2 * node + 1];
    float self0 = LEAKY(asrc[2 * node] + ad0);
    float self1 = LEAKY(asrc[2 * node + 1] + ad1);

    // max phase; cache first chunk
    int e0 = off + lane;
    int s_reg = 0;
    float a0_reg = -1e30f, a1_reg = -1e30f;
    if (e0 < end) {
        s_reg = csr[e0];
        float2 as = *(const float2*)&asrc[2 * s_reg];
        a0_reg = LEAKY(as.x + ad0);
        a1_reg = LEAKY(as.y + ad1);
    }
    float m0 = fmaxf(self0, a0_reg), m1 = fmaxf(self1, a1_reg);
    for (int e = off + 64 + lane; e < end; e += 64) {
        int s = csr[e];
        float2 as = *(const float2*)&asrc[2 * s];
        m0 = fmaxf(m0, LEAKY(as.x + ad0));
        m1 = fmaxf(m1, LEAKY(as.y + ad1));
    }
#pragma unroll
    for (int o = 32; o > 0; o >>= 1) {
        m0 = fmaxf(m0, __shfl_xor(m0, o));
        m1 = fmaxf(m1, __shfl_xor(m1, o));
    }

    float sum0, sum1, acc0, acc1;
    {
        unsigned u = hpk[(size_t)node * 64 + lane];
        float ws0 = __expf(self0 - m0), ws1 = __expf(self1 - m1);
        sum0 = ws0; sum1 = ws1;
        acc0 = ws0 * bf_lo(u);
        acc1 = ws1 * bf_hi(u);
    }

    for (int chunk = off; chunk < end; chunk += 64) {
        float w0, w1;
        int s;
        if (chunk == off) {
            s = s_reg;
            bool v = e0 < end;
            w0 = v ? __expf(a0_reg - m0) : 0.f;
            w1 = v ? __expf(a1_reg - m1) : 0.f;
        } else {
            int e = chunk + lane;
            s = 0;
            w0 = 0.f; w1 = 0.f;
            if (e < end) {
                s = csr[e];
                float2 as = *(const float2*)&asrc[2 * s];
                w0 = __expf(LEAKY(as.x + ad0) - m0);
                w1 = __expf(LEAKY(as.y + ad1) - m1);
            }
        }
        float t0 = w0, t1 = w1;
#pragma unroll
        for (int o = 32; o > 0; o >>= 1) {
            t0 += __shfl_xor(t0, o);
            t1 += __shfl_xor(t1, o);
        }
        sum0 += t0; sum1 += t1;

        int cnt = min(64, end - chunk);
        int j = 0;
        for (; j + 4 <= cnt; j += 4) {
            int   sj0 = __builtin_amdgcn_readlane(s, j);
            int   sj1 = __builtin_amdgcn_readlane(s, j + 1);
            int   sj2 = __builtin_amdgcn_readlane(s, j + 2);
            int   sj3 = __builtin_amdgcn_readlane(s, j + 3);
            float p0 = readlane_f(w0, j),     q0 = readlane_f(w1, j);
            float p1 = readlane_f(w0, j + 1), q1 = readlane_f(w1, j + 1);
            float p2 = readlane_f(w0, j + 2), q2 = readlane_f(w1, j + 2);
            float p3 = readlane_f(w0, j + 3), q3 = readlane_f(w1, j + 3);
            unsigned u0 = hpk[(size_t)sj0 * 64 + lane];
            unsigned u1 = hpk[(size_t)sj1 * 64 + lane];
            unsigned u2 = hpk[(size_t)sj2 * 64 + lane];
            unsigned u3 = hpk[(size_t)sj3 * 64 + lane];
            acc0 = fmaf(p0, bf_lo(u0), acc0); acc1 = fmaf(q0, bf_hi(u0), acc1);
            acc0 = fmaf(p1, bf_lo(u1), acc0); acc1 = fmaf(q1, bf_hi(u1), acc1);
            acc0 = fmaf(p2, bf_lo(u2), acc0); acc1 = fmaf(q2, bf_hi(u2), acc1);
            acc0 = fmaf(p3, bf_lo(u3), acc0); acc1 = fmaf(q3, bf_hi(u3), acc1);
        }
        for (; j < cnt; ++j) {
            int   sj = __builtin_amdgcn_readlane(s, j);
            float p = readlane_f(w0, j), q = readlane_f(w1, j);
            unsigned u = hpk[(size_t)sj * 64 + lane];
            acc0 = fmaf(p, bf_lo(u), acc0);
            acc1 = fmaf(q, bf_hi(u), acc1);
        }
    }
    float o0 = acc0 / (sum0 + 1e-16f) + bias[lane];
    float o1 = acc1 / (sum1 + 1e-16f) + bias[64 + lane];
    out[(size_t)node * 128 + lane] = fmaxf(o0, 0.f);
    out[(size_t)node * 128 + 64 + lane] = fmaxf(o1, 0.f);
}

// layer2: one wave per node, bf16 gather, no relu
__global__ void agg_layer2(const unsigned short* __restrict__ hb, const float* __restrict__ asrc,
                           const float* __restrict__ adst, const int* __restrict__ offs,
                           const int* __restrict__ csr, const float* __restrict__ bias,
                           float* __restrict__ out, int N) {
    int node = (blockIdx.x * blockDim.x + threadIdx.x) >> 6;
    int lane = threadIdx.x & 63;
    if (node >= N) return;
    int off = offs[node], end = offs[node + 1];
    float ad = adst[node];
    float self = LEAKY(asrc[node] + ad);

    int e0 = off + lane;
    int s_reg = 0;
    float a_reg = -1e30f;
    if (e0 < end) {
        s_reg = csr[e0];
        a_reg = LEAKY(asrc[s_reg] + ad);
    }
    float m = fmaxf(self, a_reg);
    for (int e = off + 64 + lane; e < end; e += 64) {
        m = fmaxf(m, LEAKY(asrc[csr[e]] + ad));
    }
#pragma unroll
    for (int o = 32; o > 0; o >>= 1) m = fmaxf(m, __shfl_xor(m, o));

    float wself = __expf(self - m);
    float sum = wself;
    float acc = wself * __uint_as_float((unsigned)hb[(size_t)node * 64 + lane] << 16);

    for (int chunk = off; chunk < end; chunk += 64) {
        float w;
        int s;
        if (chunk == off) {
            s = s_reg;
            w = (e0 < end) ? __expf(a_reg - m) : 0.f;
        } else {
            int e = chunk + lane;
            s = 0;
            w = 0.f;
            if (e < end) {
                s = csr[e];
                w = __expf(LEAKY(asrc[s] + ad) - m);
            }
        }
        float t = w;
#pragma unroll
        for (int o = 32; o > 0; o >>= 1) t += __shfl_xor(t, o);
        sum += t;

        int cnt = min(64, end - chunk);
        int j = 0;
        for (; j + 4 <= cnt; j += 4) {
            int   sj0 = __builtin_amdgcn_readlane(s, j);
            int   sj1 = __builtin_amdgcn_readlane(s, j + 1);
            int   sj2 = __builtin_amdgcn_readlane(s, j + 2);
            int   sj3 = __builtin_amdgcn_readlane(s, j + 3);
            float p0 = readlane_f(w, j);
            float p1 = readlane_f(w, j + 1);
            float p2 = readlane_f(w, j + 2);
            float p3 = readlane_f(w, j + 3);
            float v0 = __uint_as_float((unsigned)hb[(size_t)sj0 * 64 + lane] << 16);
            float v1 = __uint_as_float((unsigned)hb[(size_t)sj1 * 64 + lane] << 16);
            float v2 = __uint_as_float((unsigned)hb[(size_t)sj2 * 64 + lane] << 16);
            float v3 = __uint_as_float((unsigned)hb[(size_t)sj3 * 64 + lane] << 16);
            acc = fmaf(p0, v0, acc);
            acc = fmaf(p1, v1, acc);
            acc = fmaf(p2, v2, acc);
            acc = fmaf(p3, v3, acc);
        }
        for (; j < cnt; ++j) {
            int   sj = __builtin_amdgcn_readlane(s, j);
            float p = readlane_f(w, j);
            acc = fmaf(p, __uint_as_float((unsigned)hb[(size_t)sj * 64 + lane] << 16), acc);
        }
    }
    out[(size_t)node * 64 + lane] = acc / (sum + 1e-16f) + bias[lane];
}

// ---------------------------------------------------------------- host
extern "C" void kernel_launch(void* const* d_in, const int* in_sizes, int n_in,
                              void* d_out, int out_size, void* d_ws, size_t ws_size,
                              hipStream_t stream) {
    const float* x        = (const float*)d_in[0];
    const int* ei         = (const int*)d_in[1];
    const float* W1       = (const float*)d_in[2];
    const float* att_src1 = (const float*)d_in[3];
    const float* att_dst1 = (const float*)d_in[4];
    const float* bias1    = (const float*)d_in[5];
    const float* W2       = (const float*)d_in[6];
    const float* att_src2 = (const float*)d_in[7];
    const float* att_dst2 = (const float*)d_in[8];
    const float* bias2    = (const float*)d_in[9];

    const int N = in_sizes[0] / 128;  // 100000
    const int E = in_sizes[1] / 2;    // 1600000

    char* base = (char*)d_ws;
    size_t off = 0;
    auto alloc = [&](size_t bytes) {
        char* p = base + off;
        off = (off + bytes + 255) & ~(size_t)255;
        return p;
    };
    int*      deg     = (int*)alloc((size_t)N * 4);
    int*      offsets = (int*)alloc((size_t)(N + 1) * 4);
    int*      cursor  = (int*)alloc((size_t)N * 4);
    int*      bsum    = (int*)alloc(4096);
    int*      csr     = (int*)alloc((size_t)E * 4);
    float*    h1      = (float*)alloc((size_t)N * 128 * 4);   // layer1 features (fp32)
    float*    out1    = (float*)alloc((size_t)N * 128 * 4);   // layer1 output / layer2 GEMM input
    unsigned* hpk     = (unsigned*)alloc((size_t)N * 64 * 4); // packed bf16 pairs, layer1
    unsigned short* hb = (unsigned short*)alloc((size_t)N * 64 * 2); // bf16, layer2
    float*    asrc1   = (float*)alloc((size_t)N * 2 * 4);
    float*    adst1   = (float*)alloc((size_t)N * 2 * 4);
    float*    asrc2   = (float*)alloc((size_t)N * 4);
    float*    adst2   = (float*)alloc((size_t)N * 4);
    float*    h2      = h1;  // fp32 layer2 features alias (h1 dead after att_scores_h2/agg)

    const int nb = (N + 2047) / 2048;

    hipMemsetAsync(deg, 0, (size_t)N * 4, stream);
    hist_dst<<<(E + 255) / 256, 256, 0, stream>>>(ei, E, deg);
    scan_phase1<<<nb, 256, 0, stream>>>(deg, N, bsum);
    scan_phase2<<<1, 64, 0, stream>>>(bsum, nb, offsets, N);
    scan_phase3<<<nb, 256, 0, stream>>>(deg, N, bsum, offsets);
    hipMemcpyAsync(cursor, offsets, (size_t)N * 4, hipMemcpyDeviceToDevice, stream);
    scatter_csr<<<(E + 255) / 256, 256, 0, stream>>>(ei, E, cursor, csr);

    const int nwave_blocks = (N + 3) / 4;

    // --- layer 1 ---
    gemm_rl<128><<<512, 256, 0, stream>>>(x, W1, h1, N);
    att_scores_h2<<<nwave_blocks, 256, 0, stream>>>(h1, att_src1, att_dst1, asrc1, adst1, hpk, N);
    agg_layer1<<<nwave_blocks, 256, 0, stream>>>(hpk, asrc1, adst1, offsets, csr, bias1, out1, N);

    // --- layer 2 ---
    gemm_rl<64><<<512, 256, 0, stream>>>(out1, W2, h2, N);
    att_scores_h1<<<nwave_blocks, 256, 0, stream>>>(h2, att_src2, att_dst2, asrc2, adst2, hb, N);
    agg_layer2<<<nwave_blocks, 256, 0, stream>>>(hb, asrc2, adst2, offsets, csr, bias2,
                                                 (float*)d_out, N);
}

// Round 6
// 473.933 us; speedup vs baseline: 1.6491x; 1.6491x over previous
//
#include <hip/hip_runtime.h>
#include <hip/hip_bf16.h>
#include <cstdint>
#include <cstddef>

#define LEAKY(x) ((x) > 0.f ? (x) : 0.2f * (x))

__device__ __forceinline__ float readlane_f(float v, int l) {
    return __int_as_float(__builtin_amdgcn_readlane(__float_as_int(v), l));
}
// round-to-nearest-even fp32 -> bf16 bits
__device__ __forceinline__ unsigned short f2bf(float f) {
    unsigned x = __float_as_uint(f);
    return (unsigned short)((x + 0x7fffu + ((x >> 16) & 1u)) >> 16);
}
__device__ __forceinline__ float bf_lo(unsigned u) { return __uint_as_float(u << 16); }
__device__ __forceinline__ float bf_hi(unsigned u) { return __uint_as_float(u & 0xffff0000u); }

// ---------------------------------------------------------------- CSR build
__global__ void hist_dst(const int* __restrict__ ei, int E, int* __restrict__ deg) {
    int e = blockIdx.x * 256 + threadIdx.x;
    if (e < E) atomicAdd(&deg[ei[E + e]], 1);
}

__global__ void scan_phase1(const int* __restrict__ deg, int n, int* __restrict__ bsum) {
    __shared__ int red[256];
    int t = threadIdx.x;
    int base = blockIdx.x * 2048;
    int s = 0;
#pragma unroll
    for (int i = 0; i < 8; ++i) {
        int idx = base + t * 8 + i;
        s += (idx < n) ? deg[idx] : 0;
    }
    red[t] = s;
    __syncthreads();
    for (int o = 128; o > 0; o >>= 1) {
        if (t < o) red[t] += red[t + o];
        __syncthreads();
    }
    if (t == 0) bsum[blockIdx.x] = red[0];
}

__global__ void scan_phase2(int* __restrict__ bsum, int nb, int* __restrict__ offsets, int n) {
    if (threadIdx.x == 0 && blockIdx.x == 0) {
        int run = 0;
        for (int i = 0; i < nb; ++i) {
            int v = bsum[i];
            bsum[i] = run;
            run += v;
        }
        offsets[n] = run;
    }
}

__global__ void scan_phase3(const int* __restrict__ deg, int n, const int* __restrict__ bsum,
                            int* __restrict__ out) {
    __shared__ int sh[256];
    int t = threadIdx.x;
    int base = blockIdx.x * 2048;
    int loc[8];
    int s = 0;
#pragma unroll
    for (int i = 0; i < 8; ++i) {
        int idx = base + t * 8 + i;
        loc[i] = (idx < n) ? deg[idx] : 0;
        s += loc[i];
    }
    sh[t] = s;
    __syncthreads();
    for (int o = 1; o < 256; o <<= 1) {
        int add = (t >= o) ? sh[t - o] : 0;
        __syncthreads();
        sh[t] += add;
        __syncthreads();
    }
    int excl = sh[t] - s + bsum[blockIdx.x];
#pragma unroll
    for (int i = 0; i < 8; ++i) {
        int idx = base + t * 8 + i;
        if (idx < n) out[idx] = excl;
        excl += loc[i];
    }
}

__global__ void scatter_csr(const int* __restrict__ ei, int E, int* __restrict__ cursor,
                            int* __restrict__ csr) {
    int e = blockIdx.x * 256 + threadIdx.x;
    if (e < E) {
        int d = ei[E + e];
        int s = ei[e];
        int pos = atomicAdd(&cursor[d], 1);
        csr[pos] = s;
    }
}

// ---------------------------------------------------------------- GEMM (K=128 fixed)
// C[M,Nout] = A[M,128] @ B[128,Nout]; BM=64, BN=64, BK=16; 16x16 threads, 4x4 micro-tile
__global__ void gemm_k128(const float* __restrict__ A, const float* __restrict__ B,
                          float* __restrict__ C, int M, int Nout) {
    __shared__ float As[16][68];
    __shared__ float Bs[16][68];
    const int tid = threadIdx.y * 16 + threadIdx.x;
    const int row0 = blockIdx.x * 64;
    const int col0 = blockIdx.y * 64;
    float acc[4][4] = {};
    for (int k0 = 0; k0 < 128; k0 += 16) {
        {
            int idx = tid * 4;
            int r = idx >> 4;
            int c = idx & 15;
            float4 v = make_float4(0.f, 0.f, 0.f, 0.f);
            if (row0 + r < M)
                v = *(const float4*)(A + (size_t)(row0 + r) * 128 + k0 + c);
            As[c][r] = v.x; As[c + 1][r] = v.y; As[c + 2][r] = v.z; As[c + 3][r] = v.w;
        }
        {
            int idx = tid * 4;
            int r = idx >> 6;
            int c = idx & 63;
            float4 v = *(const float4*)(B + (size_t)(k0 + r) * Nout + col0 + c);
            Bs[r][c] = v.x; Bs[r][c + 1] = v.y; Bs[r][c + 2] = v.z; Bs[r][c + 3] = v.w;
        }
        __syncthreads();
#pragma unroll
        for (int kk = 0; kk < 16; ++kk) {
            float a[4], b[4];
#pragma unroll
            for (int i = 0; i < 4; ++i) a[i] = As[kk][threadIdx.y * 4 + i];
#pragma unroll
            for (int j = 0; j < 4; ++j) b[j] = Bs[kk][threadIdx.x * 4 + j];
#pragma unroll
            for (int i = 0; i < 4; ++i)
#pragma unroll
                for (int j = 0; j < 4; ++j) acc[i][j] += a[i] * b[j];
        }
        __syncthreads();
    }
#pragma unroll
    for (int i = 0; i < 4; ++i) {
        int r = row0 + threadIdx.y * 4 + i;
        if (r < M) {
#pragma unroll
            for (int j = 0; j < 4; ++j)
                C[(size_t)r * Nout + col0 + threadIdx.x * 4 + j] = acc[i][j];
        }
    }
}

// ---------------------------------------------------------------- attention scores (+ bf16 pack)
__global__ void att_scores_h2(const float* __restrict__ h, const float* __restrict__ att_src,
                              const float* __restrict__ att_dst, float* __restrict__ asrc,
                              float* __restrict__ adst, unsigned* __restrict__ hpk, int N) {
    int wid = (blockIdx.x * blockDim.x + threadIdx.x) >> 6;
    int lane = threadIdx.x & 63;
    if (wid >= N) return;
    const float* row = h + (size_t)wid * 128;
    float h0 = row[lane], h1 = row[64 + lane];
    hpk[(size_t)wid * 64 + lane] = (unsigned)f2bf(h0) | ((unsigned)f2bf(h1) << 16);
    float s0 = h0 * att_src[lane], s1 = h1 * att_src[64 + lane];
    float d0 = h0 * att_dst[lane], d1 = h1 * att_dst[64 + lane];
    for (int m = 32; m > 0; m >>= 1) {
        s0 += __shfl_xor(s0, m);
        s1 += __shfl_xor(s1, m);
        d0 += __shfl_xor(d0, m);
        d1 += __shfl_xor(d1, m);
    }
    if (lane == 0) {
        asrc[wid * 2] = s0; asrc[wid * 2 + 1] = s1;
        adst[wid * 2] = d0; adst[wid * 2 + 1] = d1;
    }
}

__global__ void att_scores_h1(const float* __restrict__ h, const float* __restrict__ att_src,
                              const float* __restrict__ att_dst, float* __restrict__ asrc,
                              float* __restrict__ adst, unsigned short* __restrict__ hb, int N) {
    int wid = (blockIdx.x * blockDim.x + threadIdx.x) >> 6;
    int lane = threadIdx.x & 63;
    if (wid >= N) return;
    float hv = h[(size_t)wid * 64 + lane];
    hb[(size_t)wid * 64 + lane] = f2bf(hv);
    float s = hv * att_src[lane];
    float d = hv * att_dst[lane];
    for (int m = 32; m > 0; m >>= 1) {
        s += __shfl_xor(s, m);
        d += __shfl_xor(d, m);
    }
    if (lane == 0) {
        asrc[wid] = s;
        adst[wid] = d;
    }
}

// ---------------------------------------------------------------- fused softmax+aggregate
// layer1: ONE wave per node, both heads from one packed uint gather.
__global__ void agg_layer1(const unsigned* __restrict__ hpk, const float* __restrict__ asrc,
                           const float* __restrict__ adst, const int* __restrict__ offs,
                           const int* __restrict__ csr, const float* __restrict__ bias,
                           float* __restrict__ out, int N) {
    int node = (blockIdx.x * blockDim.x + threadIdx.x) >> 6;
    int lane = threadIdx.x & 63;
    if (node >= N) return;
    int off = offs[node], end = offs[node + 1];
    float ad0 = adst[2 * node], ad1 = adst[2 * node + 1];
    float self0 = LEAKY(asrc[2 * node] + ad0);
    float self1 = LEAKY(asrc[2 * node + 1] + ad1);

    // max phase; cache first chunk
    int e0 = off + lane;
    int s_reg = 0;
    float a0_reg = -1e30f, a1_reg = -1e30f;
    if (e0 < end) {
        s_reg = csr[e0];
        float2 as = *(const float2*)&asrc[2 * s_reg];
        a0_reg = LEAKY(as.x + ad0);
        a1_reg = LEAKY(as.y + ad1);
    }
    float m0 = fmaxf(self0, a0_reg), m1 = fmaxf(self1, a1_reg);
    for (int e = off + 64 + lane; e < end; e += 64) {
        int s = csr[e];
        float2 as = *(const float2*)&asrc[2 * s];
        m0 = fmaxf(m0, LEAKY(as.x + ad0));
        m1 = fmaxf(m1, LEAKY(as.y + ad1));
    }
#pragma unroll
    for (int o = 32; o > 0; o >>= 1) {
        m0 = fmaxf(m0, __shfl_xor(m0, o));
        m1 = fmaxf(m1, __shfl_xor(m1, o));
    }

    float sum0, sum1, acc0, acc1;
    {
        unsigned u = hpk[(size_t)node * 64 + lane];
        float ws0 = __expf(self0 - m0), ws1 = __expf(self1 - m1);
        sum0 = ws0; sum1 = ws1;
        acc0 = ws0 * bf_lo(u);
        acc1 = ws1 * bf_hi(u);
    }

    for (int chunk = off; chunk < end; chunk += 64) {
        float w0, w1;
        int s;
        if (chunk == off) {
            s = s_reg;
            bool v = e0 < end;
            w0 = v ? __expf(a0_reg - m0) : 0.f;
            w1 = v ? __expf(a1_reg - m1) : 0.f;
        } else {
            int e = chunk + lane;
            s = 0;
            w0 = 0.f; w1 = 0.f;
            if (e < end) {
                s = csr[e];
                float2 as = *(const float2*)&asrc[2 * s];
                w0 = __expf(LEAKY(as.x + ad0) - m0);
                w1 = __expf(LEAKY(as.y + ad1) - m1);
            }
        }
        float t0 = w0, t1 = w1;
#pragma unroll
        for (int o = 32; o > 0; o >>= 1) {
            t0 += __shfl_xor(t0, o);
            t1 += __shfl_xor(t1, o);
        }
        sum0 += t0; sum1 += t1;

        int cnt = min(64, end - chunk);
        int j = 0;
        for (; j + 4 <= cnt; j += 4) {
            int   sj0 = __builtin_amdgcn_readlane(s, j);
            int   sj1 = __builtin_amdgcn_readlane(s, j + 1);
            int   sj2 = __builtin_amdgcn_readlane(s, j + 2);
            int   sj3 = __builtin_amdgcn_readlane(s, j + 3);
            float p0 = readlane_f(w0, j),     q0 = readlane_f(w1, j);
            float p1 = readlane_f(w0, j + 1), q1 = readlane_f(w1, j + 1);
            float p2 = readlane_f(w0, j + 2), q2 = readlane_f(w1, j + 2);
            float p3 = readlane_f(w0, j + 3), q3 = readlane_f(w1, j + 3);
            unsigned u0 = hpk[(size_t)sj0 * 64 + lane];
            unsigned u1 = hpk[(size_t)sj1 * 64 + lane];
            unsigned u2 = hpk[(size_t)sj2 * 64 + lane];
            unsigned u3 = hpk[(size_t)sj3 * 64 + lane];
            acc0 = fmaf(p0, bf_lo(u0), acc0); acc1 = fmaf(q0, bf_hi(u0), acc1);
            acc0 = fmaf(p1, bf_lo(u1), acc0); acc1 = fmaf(q1, bf_hi(u1), acc1);
            acc0 = fmaf(p2, bf_lo(u2), acc0); acc1 = fmaf(q2, bf_hi(u2), acc1);
            acc0 = fmaf(p3, bf_lo(u3), acc0); acc1 = fmaf(q3, bf_hi(u3), acc1);
        }
        for (; j < cnt; ++j) {
            int   sj = __builtin_amdgcn_readlane(s, j);
            float p = readlane_f(w0, j), q = readlane_f(w1, j);
            unsigned u = hpk[(size_t)sj * 64 + lane];
            acc0 = fmaf(p, bf_lo(u), acc0);
            acc1 = fmaf(q, bf_hi(u), acc1);
        }
    }
    float o0 = acc0 / (sum0 + 1e-16f) + bias[lane];
    float o1 = acc1 / (sum1 + 1e-16f) + bias[64 + lane];
    out[(size_t)node * 128 + lane] = fmaxf(o0, 0.f);
    out[(size_t)node * 128 + 64 + lane] = fmaxf(o1, 0.f);
}

// layer2: one wave per node, bf16 gather, no relu
__global__ void agg_layer2(const unsigned short* __restrict__ hb, const float* __restrict__ asrc,
                           const float* __restrict__ adst, const int* __restrict__ offs,
                           const int* __restrict__ csr, const float* __restrict__ bias,
                           float* __restrict__ out, int N) {
    int node = (blockIdx.x * blockDim.x + threadIdx.x) >> 6;
    int lane = threadIdx.x & 63;
    if (node >= N) return;
    int off = offs[node], end = offs[node + 1];
    float ad = adst[node];
    float self = LEAKY(asrc[node] + ad);

    int e0 = off + lane;
    int s_reg = 0;
    float a_reg = -1e30f;
    if (e0 < end) {
        s_reg = csr[e0];
        a_reg = LEAKY(asrc[s_reg] + ad);
    }
    float m = fmaxf(self, a_reg);
    for (int e = off + 64 + lane; e < end; e += 64) {
        m = fmaxf(m, LEAKY(asrc[csr[e]] + ad));
    }
#pragma unroll
    for (int o = 32; o > 0; o >>= 1) m = fmaxf(m, __shfl_xor(m, o));

    float wself = __expf(self - m);
    float sum = wself;
    float acc = wself * __uint_as_float((unsigned)hb[(size_t)node * 64 + lane] << 16);

    for (int chunk = off; chunk < end; chunk += 64) {
        float w;
        int s;
        if (chunk == off) {
            s = s_reg;
            w = (e0 < end) ? __expf(a_reg - m) : 0.f;
        } else {
            int e = chunk + lane;
            s = 0;
            w = 0.f;
            if (e < end) {
                s = csr[e];
                w = __expf(LEAKY(asrc[s] + ad) - m);
            }
        }
        float t = w;
#pragma unroll
        for (int o = 32; o > 0; o >>= 1) t += __shfl_xor(t, o);
        sum += t;

        int cnt = min(64, end - chunk);
        int j = 0;
        for (; j + 4 <= cnt; j += 4) {
            int   sj0 = __builtin_amdgcn_readlane(s, j);
            int   sj1 = __builtin_amdgcn_readlane(s, j + 1);
            int   sj2 = __builtin_amdgcn_readlane(s, j + 2);
            int   sj3 = __builtin_amdgcn_readlane(s, j + 3);
            float p0 = readlane_f(w, j);
            float p1 = readlane_f(w, j + 1);
            float p2 = readlane_f(w, j + 2);
            float p3 = readlane_f(w, j + 3);
            float v0 = __uint_as_float((unsigned)hb[(size_t)sj0 * 64 + lane] << 16);
            float v1 = __uint_as_float((unsigned)hb[(size_t)sj1 * 64 + lane] << 16);
            float v2 = __uint_as_float((unsigned)hb[(size_t)sj2 * 64 + lane] << 16);
            float v3 = __uint_as_float((unsigned)hb[(size_t)sj3 * 64 + lane] << 16);
            acc = fmaf(p0, v0, acc);
            acc = fmaf(p1, v1, acc);
            acc = fmaf(p2, v2, acc);
            acc = fmaf(p3, v3, acc);
        }
        for (; j < cnt; ++j) {
            int   sj = __builtin_amdgcn_readlane(s, j);
            float p = readlane_f(w, j);
            acc = fmaf(p, __uint_as_float((unsigned)hb[(size_t)sj * 64 + lane] << 16), acc);
        }
    }
    out[(size_t)node * 64 + lane] = acc / (sum + 1e-16f) + bias[lane];
}

// ---------------------------------------------------------------- host
extern "C" void kernel_launch(void* const* d_in, const int* in_sizes, int n_in,
                              void* d_out, int out_size, void* d_ws, size_t ws_size,
                              hipStream_t stream) {
    const float* x        = (const float*)d_in[0];
    const int* ei         = (const int*)d_in[1];
    const float* W1       = (const float*)d_in[2];
    const float* att_src1 = (const float*)d_in[3];
    const float* att_dst1 = (const float*)d_in[4];
    const float* bias1    = (const float*)d_in[5];
    const float* W2       = (const float*)d_in[6];
    const float* att_src2 = (const float*)d_in[7];
    const float* att_dst2 = (const float*)d_in[8];
    const float* bias2    = (const float*)d_in[9];

    const int N = in_sizes[0] / 128;  // 100000
    const int E = in_sizes[1] / 2;    // 1600000

    char* base = (char*)d_ws;
    size_t off = 0;
    auto alloc = [&](size_t bytes) {
        char* p = base + off;
        off = (off + bytes + 255) & ~(size_t)255;
        return p;
    };
    int*      deg     = (int*)alloc((size_t)N * 4);
    int*      offsets = (int*)alloc((size_t)(N + 1) * 4);
    int*      cursor  = (int*)alloc((size_t)N * 4);
    int*      bsum    = (int*)alloc(4096);
    int*      csr     = (int*)alloc((size_t)E * 4);
    float*    h1      = (float*)alloc((size_t)N * 128 * 4);   // layer1 features (fp32)
    float*    out1    = (float*)alloc((size_t)N * 128 * 4);   // layer1 output / layer2 GEMM input
    unsigned* hpk     = (unsigned*)alloc((size_t)N * 64 * 4); // packed bf16 pairs, layer1
    unsigned short* hb = (unsigned short*)alloc((size_t)N * 64 * 2); // bf16, layer2
    float*    asrc1   = (float*)alloc((size_t)N * 2 * 4);
    float*    adst1   = (float*)alloc((size_t)N * 2 * 4);
    float*    asrc2   = (float*)alloc((size_t)N * 4);
    float*    adst2   = (float*)alloc((size_t)N * 4);
    float*    h2      = h1;  // fp32 layer2 features alias (h1 dead after layer1 agg)

    const int nb = (N + 2047) / 2048;

    hipMemsetAsync(deg, 0, (size_t)N * 4, stream);
    hist_dst<<<(E + 255) / 256, 256, 0, stream>>>(ei, E, deg);
    scan_phase1<<<nb, 256, 0, stream>>>(deg, N, bsum);
    scan_phase2<<<1, 64, 0, stream>>>(bsum, nb, offsets, N);
    scan_phase3<<<nb, 256, 0, stream>>>(deg, N, bsum, offsets);
    hipMemcpyAsync(cursor, offsets, (size_t)N * 4, hipMemcpyDeviceToDevice, stream);
    scatter_csr<<<(E + 255) / 256, 256, 0, stream>>>(ei, E, cursor, csr);

    const int mblocks = (N + 63) / 64;
    const int nwave_blocks = (N + 3) / 4;

    // --- layer 1 ---
    gemm_k128<<<dim3(mblocks, 2), dim3(16, 16), 0, stream>>>(x, W1, h1, N, 128);
    att_scores_h2<<<nwave_blocks, 256, 0, stream>>>(h1, att_src1, att_dst1, asrc1, adst1, hpk, N);
    agg_layer1<<<nwave_blocks, 256, 0, stream>>>(hpk, asrc1, adst1, offsets, csr, bias1, out1, N);

    // --- layer 2 ---
    gemm_k128<<<dim3(mblocks, 1), dim3(16, 16), 0, stream>>>(out1, W2, h2, N, 64);
    att_scores_h1<<<nwave_blocks, 256, 0, stream>>>(h2, att_src2, att_dst2, asrc2, adst2, hb, N);
    agg_layer2<<<nwave_blocks, 256, 0, stream>>>(hb, asrc2, adst2, offsets, csr, bias2,
                                                 (float*)d_out, N);
}

// Round 7
// 434.505 us; speedup vs baseline: 1.7988x; 1.0907x over previous
//
#include <hip/hip_runtime.h>
#include <hip/hip_bf16.h>
#include <cstdint>
#include <cstddef>

#define LEAKY(x) ((x) > 0.f ? (x) : 0.2f * (x))

__device__ __forceinline__ float readlane_f(float v, int l) {
    return __int_as_float(__builtin_amdgcn_readlane(__float_as_int(v), l));
}
// round-to-nearest-even fp32 -> bf16 bits
__device__ __forceinline__ unsigned short f2bf(float f) {
    unsigned x = __float_as_uint(f);
    return (unsigned short)((x + 0x7fffu + ((x >> 16) & 1u)) >> 16);
}
__device__ __forceinline__ float bf_lo(unsigned u) { return __uint_as_float(u << 16); }
__device__ __forceinline__ float bf_hi(unsigned u) { return __uint_as_float(u & 0xffff0000u); }

// ---------------------------------------------------------------- CSR build
__global__ void hist_dst(const int* __restrict__ ei, int E, int* __restrict__ deg) {
    int e = blockIdx.x * 256 + threadIdx.x;
    if (e < E) atomicAdd(&deg[ei[E + e]], 1);
}

__global__ void scan_phase1(const int* __restrict__ deg, int n, int* __restrict__ bsum) {
    __shared__ int red[256];
    int t = threadIdx.x;
    int base = blockIdx.x * 2048;
    int s = 0;
#pragma unroll
    for (int i = 0; i < 8; ++i) {
        int idx = base + t * 8 + i;
        s += (idx < n) ? deg[idx] : 0;
    }
    red[t] = s;
    __syncthreads();
    for (int o = 128; o > 0; o >>= 1) {
        if (t < o) red[t] += red[t + o];
        __syncthreads();
    }
    if (t == 0) bsum[blockIdx.x] = red[0];
}

__global__ void scan_phase2(int* __restrict__ bsum, int nb, int* __restrict__ offsets, int n) {
    if (threadIdx.x == 0 && blockIdx.x == 0) {
        int run = 0;
        for (int i = 0; i < nb; ++i) {
            int v = bsum[i];
            bsum[i] = run;
            run += v;
        }
        offsets[n] = run;
    }
}

// writes both offsets and cursor (cursor = working copy for the scatter)
__global__ void scan_phase3(const int* __restrict__ deg, int n, const int* __restrict__ bsum,
                            int* __restrict__ out, int* __restrict__ cursor) {
    __shared__ int sh[256];
    int t = threadIdx.x;
    int base = blockIdx.x * 2048;
    int loc[8];
    int s = 0;
#pragma unroll
    for (int i = 0; i < 8; ++i) {
        int idx = base + t * 8 + i;
        loc[i] = (idx < n) ? deg[idx] : 0;
        s += loc[i];
    }
    sh[t] = s;
    __syncthreads();
    for (int o = 1; o < 256; o <<= 1) {
        int add = (t >= o) ? sh[t - o] : 0;
        __syncthreads();
        sh[t] += add;
        __syncthreads();
    }
    int excl = sh[t] - s + bsum[blockIdx.x];
#pragma unroll
    for (int i = 0; i < 8; ++i) {
        int idx = base + t * 8 + i;
        if (idx < n) {
            out[idx] = excl;
            cursor[idx] = excl;
        }
        excl += loc[i];
    }
}

// ---------------------------------------------------------------- fused: GEMM1 (K=128,NOUT=128) + edge scatter
// First 2*mblocks blocks: 64x64 GEMM tiles of C[M,128] = A[M,128]@B[128,128].
// Remaining blocks: scatter_csr (atomic cursor).
// The two tasks are independent; scatter is latency/write-bound (VALU ~0%),
// GEMM is VALU-bound -> co-scheduling hides the GEMM entirely.
__global__ __launch_bounds__(256) void fused_gemm1_scatter(
    const float* __restrict__ A, const float* __restrict__ B, float* __restrict__ C, int M,
    const int* __restrict__ ei, int E, int* __restrict__ cursor, int* __restrict__ csr,
    int mblocks) {
    __shared__ float As[16][68];
    __shared__ float Bs[16][68];
    const int gemmBlocks = mblocks * 2;
    if ((int)blockIdx.x < gemmBlocks) {
        const int tid = threadIdx.x;
        const int tx = tid & 15, ty = tid >> 4;
        const int by = ((int)blockIdx.x >= mblocks) ? 1 : 0;
        const int bx = (int)blockIdx.x - by * mblocks;
        const int row0 = bx * 64;
        const int col0 = by * 64;
        float acc[4][4] = {};
        for (int k0 = 0; k0 < 128; k0 += 16) {
            {
                int idx = tid * 4;
                int r = idx >> 4;
                int c = idx & 15;
                float4 v = make_float4(0.f, 0.f, 0.f, 0.f);
                if (row0 + r < M)
                    v = *(const float4*)(A + (size_t)(row0 + r) * 128 + k0 + c);
                As[c][r] = v.x; As[c + 1][r] = v.y; As[c + 2][r] = v.z; As[c + 3][r] = v.w;
            }
            {
                int idx = tid * 4;
                int r = idx >> 6;
                int c = idx & 63;
                float4 v = *(const float4*)(B + (size_t)(k0 + r) * 128 + col0 + c);
                Bs[r][c] = v.x; Bs[r][c + 1] = v.y; Bs[r][c + 2] = v.z; Bs[r][c + 3] = v.w;
            }
            __syncthreads();
#pragma unroll
            for (int kk = 0; kk < 16; ++kk) {
                float a[4], b[4];
#pragma unroll
                for (int i = 0; i < 4; ++i) a[i] = As[kk][ty * 4 + i];
#pragma unroll
                for (int j = 0; j < 4; ++j) b[j] = Bs[kk][tx * 4 + j];
#pragma unroll
                for (int i = 0; i < 4; ++i)
#pragma unroll
                    for (int j = 0; j < 4; ++j) acc[i][j] += a[i] * b[j];
            }
            __syncthreads();
        }
#pragma unroll
        for (int i = 0; i < 4; ++i) {
            int r = row0 + ty * 4 + i;
            if (r < M) {
#pragma unroll
                for (int j = 0; j < 4; ++j)
                    C[(size_t)r * 128 + col0 + tx * 4 + j] = acc[i][j];
            }
        }
    } else {
        int e = ((int)blockIdx.x - gemmBlocks) * 256 + threadIdx.x;
        if (e < E) {
            int d = ei[E + e];
            int s = ei[e];
            int pos = atomicAdd(&cursor[d], 1);
            csr[pos] = s;
        }
    }
}

// ---------------------------------------------------------------- GEMM (K=128 fixed) for layer 2
__global__ void gemm_k128(const float* __restrict__ A, const float* __restrict__ B,
                          float* __restrict__ C, int M, int Nout) {
    __shared__ float As[16][68];
    __shared__ float Bs[16][68];
    const int tid = threadIdx.y * 16 + threadIdx.x;
    const int row0 = blockIdx.x * 64;
    const int col0 = blockIdx.y * 64;
    float acc[4][4] = {};
    for (int k0 = 0; k0 < 128; k0 += 16) {
        {
            int idx = tid * 4;
            int r = idx >> 4;
            int c = idx & 15;
            float4 v = make_float4(0.f, 0.f, 0.f, 0.f);
            if (row0 + r < M)
                v = *(const float4*)(A + (size_t)(row0 + r) * 128 + k0 + c);
            As[c][r] = v.x; As[c + 1][r] = v.y; As[c + 2][r] = v.z; As[c + 3][r] = v.w;
        }
        {
            int idx = tid * 4;
            int r = idx >> 6;
            int c = idx & 63;
            float4 v = *(const float4*)(B + (size_t)(k0 + r) * Nout + col0 + c);
            Bs[r][c] = v.x; Bs[r][c + 1] = v.y; Bs[r][c + 2] = v.z; Bs[r][c + 3] = v.w;
        }
        __syncthreads();
#pragma unroll
        for (int kk = 0; kk < 16; ++kk) {
            float a[4], b[4];
#pragma unroll
            for (int i = 0; i < 4; ++i) a[i] = As[kk][threadIdx.y * 4 + i];
#pragma unroll
            for (int j = 0; j < 4; ++j) b[j] = Bs[kk][threadIdx.x * 4 + j];
#pragma unroll
            for (int i = 0; i < 4; ++i)
#pragma unroll
                for (int j = 0; j < 4; ++j) acc[i][j] += a[i] * b[j];
        }
        __syncthreads();
    }
#pragma unroll
    for (int i = 0; i < 4; ++i) {
        int r = row0 + threadIdx.y * 4 + i;
        if (r < M) {
#pragma unroll
            for (int j = 0; j < 4; ++j)
                C[(size_t)r * Nout + col0 + threadIdx.x * 4 + j] = acc[i][j];
        }
    }
}

// ---------------------------------------------------------------- attention scores (+ bf16 pack)
__global__ void att_scores_h2(const float* __restrict__ h, const float* __restrict__ att_src,
                              const float* __restrict__ att_dst, float* __restrict__ asrc,
                              float* __restrict__ adst, unsigned* __restrict__ hpk, int N) {
    int wid = (blockIdx.x * blockDim.x + threadIdx.x) >> 6;
    int lane = threadIdx.x & 63;
    if (wid >= N) return;
    const float* row = h + (size_t)wid * 128;
    float h0 = row[lane], h1 = row[64 + lane];
    hpk[(size_t)wid * 64 + lane] = (unsigned)f2bf(h0) | ((unsigned)f2bf(h1) << 16);
    float s0 = h0 * att_src[lane], s1 = h1 * att_src[64 + lane];
    float d0 = h0 * att_dst[lane], d1 = h1 * att_dst[64 + lane];
    for (int m = 32; m > 0; m >>= 1) {
        s0 += __shfl_xor(s0, m);
        s1 += __shfl_xor(s1, m);
        d0 += __shfl_xor(d0, m);
        d1 += __shfl_xor(d1, m);
    }
    if (lane == 0) {
        asrc[wid * 2] = s0; asrc[wid * 2 + 1] = s1;
        adst[wid * 2] = d0; adst[wid * 2 + 1] = d1;
    }
}

__global__ void att_scores_h1(const float* __restrict__ h, const float* __restrict__ att_src,
                              const float* __restrict__ att_dst, float* __restrict__ asrc,
                              float* __restrict__ adst, unsigned short* __restrict__ hb, int N) {
    int wid = (blockIdx.x * blockDim.x + threadIdx.x) >> 6;
    int lane = threadIdx.x & 63;
    if (wid >= N) return;
    float hv = h[(size_t)wid * 64 + lane];
    hb[(size_t)wid * 64 + lane] = f2bf(hv);
    float s = hv * att_src[lane];
    float d = hv * att_dst[lane];
    for (int m = 32; m > 0; m >>= 1) {
        s += __shfl_xor(s, m);
        d += __shfl_xor(d, m);
    }
    if (lane == 0) {
        asrc[wid] = s;
        adst[wid] = d;
    }
}

// ---------------------------------------------------------------- fused softmax+aggregate
// layer1: ONE wave per node, both heads from one packed uint gather.
__global__ void agg_layer1(const unsigned* __restrict__ hpk, const float* __restrict__ asrc,
                           const float* __restrict__ adst, const int* __restrict__ offs,
                           const int* __restrict__ csr, const float* __restrict__ bias,
                           float* __restrict__ out, int N) {
    int node = (blockIdx.x * blockDim.x + threadIdx.x) >> 6;
    int lane = threadIdx.x & 63;
    if (node >= N) return;
    int off = offs[node], end = offs[node + 1];
    float ad0 = adst[2 * node], ad1 = adst[2 * node + 1];
    float self0 = LEAKY(asrc[2 * node] + ad0);
    float self1 = LEAKY(asrc[2 * node + 1] + ad1);

    // max phase; cache first chunk
    int e0 = off + lane;
    int s_reg = 0;
    float a0_reg = -1e30f, a1_reg = -1e30f;
    if (e0 < end) {
        s_reg = csr[e0];
        float2 as = *(const float2*)&asrc[2 * s_reg];
        a0_reg = LEAKY(as.x + ad0);
        a1_reg = LEAKY(as.y + ad1);
    }
    float m0 = fmaxf(self0, a0_reg), m1 = fmaxf(self1, a1_reg);
    for (int e = off + 64 + lane; e < end; e += 64) {
        int s = csr[e];
        float2 as = *(const float2*)&asrc[2 * s];
        m0 = fmaxf(m0, LEAKY(as.x + ad0));
        m1 = fmaxf(m1, LEAKY(as.y + ad1));
    }
#pragma unroll
    for (int o = 32; o > 0; o >>= 1) {
        m0 = fmaxf(m0, __shfl_xor(m0, o));
        m1 = fmaxf(m1, __shfl_xor(m1, o));
    }

    float sum0, sum1, acc0, acc1;
    {
        unsigned u = hpk[(size_t)node * 64 + lane];
        float ws0 = __expf(self0 - m0), ws1 = __expf(self1 - m1);
        sum0 = ws0; sum1 = ws1;
        acc0 = ws0 * bf_lo(u);
        acc1 = ws1 * bf_hi(u);
    }

    for (int chunk = off; chunk < end; chunk += 64) {
        float w0, w1;
        int s;
        if (chunk == off) {
            s = s_reg;
            bool v = e0 < end;
            w0 = v ? __expf(a0_reg - m0) : 0.f;
            w1 = v ? __expf(a1_reg - m1) : 0.f;
        } else {
            int e = chunk + lane;
            s = 0;
            w0 = 0.f; w1 = 0.f;
            if (e < end) {
                s = csr[e];
                float2 as = *(const float2*)&asrc[2 * s];
                w0 = __expf(LEAKY(as.x + ad0) - m0);
                w1 = __expf(LEAKY(as.y + ad1) - m1);
            }
        }
        float t0 = w0, t1 = w1;
#pragma unroll
        for (int o = 32; o > 0; o >>= 1) {
            t0 += __shfl_xor(t0, o);
            t1 += __shfl_xor(t1, o);
        }
        sum0 += t0; sum1 += t1;

        int cnt = min(64, end - chunk);
        int j = 0;
        for (; j + 4 <= cnt; j += 4) {
            int   sj0 = __builtin_amdgcn_readlane(s, j);
            int   sj1 = __builtin_amdgcn_readlane(s, j + 1);
            int   sj2 = __builtin_amdgcn_readlane(s, j + 2);
            int   sj3 = __builtin_amdgcn_readlane(s, j + 3);
            float p0 = readlane_f(w0, j),     q0 = readlane_f(w1, j);
            float p1 = readlane_f(w0, j + 1), q1 = readlane_f(w1, j + 1);
            float p2 = readlane_f(w0, j + 2), q2 = readlane_f(w1, j + 2);
            float p3 = readlane_f(w0, j + 3), q3 = readlane_f(w1, j + 3);
            unsigned u0 = hpk[(size_t)sj0 * 64 + lane];
            unsigned u1 = hpk[(size_t)sj1 * 64 + lane];
            unsigned u2 = hpk[(size_t)sj2 * 64 + lane];
            unsigned u3 = hpk[(size_t)sj3 * 64 + lane];
            acc0 = fmaf(p0, bf_lo(u0), acc0); acc1 = fmaf(q0, bf_hi(u0), acc1);
            acc0 = fmaf(p1, bf_lo(u1), acc0); acc1 = fmaf(q1, bf_hi(u1), acc1);
            acc0 = fmaf(p2, bf_lo(u2), acc0); acc1 = fmaf(q2, bf_hi(u2), acc1);
            acc0 = fmaf(p3, bf_lo(u3), acc0); acc1 = fmaf(q3, bf_hi(u3), acc1);
        }
        for (; j < cnt; ++j) {
            int   sj = __builtin_amdgcn_readlane(s, j);
            float p = readlane_f(w0, j), q = readlane_f(w1, j);
            unsigned u = hpk[(size_t)sj * 64 + lane];
            acc0 = fmaf(p, bf_lo(u), acc0);
            acc1 = fmaf(q, bf_hi(u), acc1);
        }
    }
    float o0 = acc0 / (sum0 + 1e-16f) + bias[lane];
    float o1 = acc1 / (sum1 + 1e-16f) + bias[64 + lane];
    out[(size_t)node * 128 + lane] = fmaxf(o0, 0.f);
    out[(size_t)node * 128 + 64 + lane] = fmaxf(o1, 0.f);
}

// layer2: one wave per node, bf16 gather, no relu
__global__ void agg_layer2(const unsigned short* __restrict__ hb, const float* __restrict__ asrc,
                           const float* __restrict__ adst, const int* __restrict__ offs,
                           const int* __restrict__ csr, const float* __restrict__ bias,
                           float* __restrict__ out, int N) {
    int node = (blockIdx.x * blockDim.x + threadIdx.x) >> 6;
    int lane = threadIdx.x & 63;
    if (node >= N) return;
    int off = offs[node], end = offs[node + 1];
    float ad = adst[node];
    float self = LEAKY(asrc[node] + ad);

    int e0 = off + lane;
    int s_reg = 0;
    float a_reg = -1e30f;
    if (e0 < end) {
        s_reg = csr[e0];
        a_reg = LEAKY(asrc[s_reg] + ad);
    }
    float m = fmaxf(self, a_reg);
    for (int e = off + 64 + lane; e < end; e += 64) {
        m = fmaxf(m, LEAKY(asrc[csr[e]] + ad));
    }
#pragma unroll
    for (int o = 32; o > 0; o >>= 1) m = fmaxf(m, __shfl_xor(m, o));

    float wself = __expf(self - m);
    float sum = wself;
    float acc = wself * __uint_as_float((unsigned)hb[(size_t)node * 64 + lane] << 16);

    for (int chunk = off; chunk < end; chunk += 64) {
        float w;
        int s;
        if (chunk == off) {
            s = s_reg;
            w = (e0 < end) ? __expf(a_reg - m) : 0.f;
        } else {
            int e = chunk + lane;
            s = 0;
            w = 0.f;
            if (e < end) {
                s = csr[e];
                w = __expf(LEAKY(asrc[s] + ad) - m);
            }
        }
        float t = w;
#pragma unroll
        for (int o = 32; o > 0; o >>= 1) t += __shfl_xor(t, o);
        sum += t;

        int cnt = min(64, end - chunk);
        int j = 0;
        for (; j + 4 <= cnt; j += 4) {
            int   sj0 = __builtin_amdgcn_readlane(s, j);
            int   sj1 = __builtin_amdgcn_readlane(s, j + 1);
            int   sj2 = __builtin_amdgcn_readlane(s, j + 2);
            int   sj3 = __builtin_amdgcn_readlane(s, j + 3);
            float p0 = readlane_f(w, j);
            float p1 = readlane_f(w, j + 1);
            float p2 = readlane_f(w, j + 2);
            float p3 = readlane_f(w, j + 3);
            float v0 = __uint_as_float((unsigned)hb[(size_t)sj0 * 64 + lane] << 16);
            float v1 = __uint_as_float((unsigned)hb[(size_t)sj1 * 64 + lane] << 16);
            float v2 = __uint_as_float((unsigned)hb[(size_t)sj2 * 64 + lane] << 16);
            float v3 = __uint_as_float((unsigned)hb[(size_t)sj3 * 64 + lane] << 16);
            acc = fmaf(p0, v0, acc);
            acc = fmaf(p1, v1, acc);
            acc = fmaf(p2, v2, acc);
            acc = fmaf(p3, v3, acc);
        }
        for (; j < cnt; ++j) {
            int   sj = __builtin_amdgcn_readlane(s, j);
            float p = readlane_f(w, j);
            acc = fmaf(p, __uint_as_float((unsigned)hb[(size_t)sj * 64 + lane] << 16), acc);
        }
    }
    out[(size_t)node * 64 + lane] = acc / (sum + 1e-16f) + bias[lane];
}

// ---------------------------------------------------------------- host
extern "C" void kernel_launch(void* const* d_in, const int* in_sizes, int n_in,
                              void* d_out, int out_size, void* d_ws, size_t ws_size,
                              hipStream_t stream) {
    const float* x        = (const float*)d_in[0];
    const int* ei         = (const int*)d_in[1];
    const float* W1       = (const float*)d_in[2];
    const float* att_src1 = (const float*)d_in[3];
    const float* att_dst1 = (const float*)d_in[4];
    const float* bias1    = (const float*)d_in[5];
    const float* W2       = (const float*)d_in[6];
    const float* att_src2 = (const float*)d_in[7];
    const float* att_dst2 = (const float*)d_in[8];
    const float* bias2    = (const float*)d_in[9];

    const int N = in_sizes[0] / 128;  // 100000
    const int E = in_sizes[1] / 2;    // 1600000

    char* base = (char*)d_ws;
    size_t off = 0;
    auto alloc = [&](size_t bytes) {
        char* p = base + off;
        off = (off + bytes + 255) & ~(size_t)255;
        return p;
    };
    int*      deg     = (int*)alloc((size_t)N * 4);
    int*      offsets = (int*)alloc((size_t)(N + 1) * 4);
    int*      cursor  = (int*)alloc((size_t)N * 4);
    int*      bsum    = (int*)alloc(4096);
    int*      csr     = (int*)alloc((size_t)E * 4);
    float*    h1      = (float*)alloc((size_t)N * 128 * 4);   // layer1 features (fp32)
    float*    out1    = (float*)alloc((size_t)N * 128 * 4);   // layer1 output / layer2 GEMM input
    unsigned* hpk     = (unsigned*)alloc((size_t)N * 64 * 4); // packed bf16 pairs, layer1
    unsigned short* hb = (unsigned short*)alloc((size_t)N * 64 * 2); // bf16, layer2
    float*    asrc1   = (float*)alloc((size_t)N * 2 * 4);
    float*    adst1   = (float*)alloc((size_t)N * 2 * 4);
    float*    asrc2   = (float*)alloc((size_t)N * 4);
    float*    adst2   = (float*)alloc((size_t)N * 4);
    float*    h2      = h1;  // fp32 layer2 features alias (h1 dead after layer1 agg)

    const int nb = (N + 2047) / 2048;
    const int mblocks = (N + 63) / 64;
    const int nwave_blocks = (N + 3) / 4;

    // --- CSR prefix (cheap) ---
    hipMemsetAsync(deg, 0, (size_t)N * 4, stream);
    hist_dst<<<(E + 255) / 256, 256, 0, stream>>>(ei, E, deg);
    scan_phase1<<<nb, 256, 0, stream>>>(deg, N, bsum);
    scan_phase2<<<1, 64, 0, stream>>>(bsum, nb, offsets, N);
    scan_phase3<<<nb, 256, 0, stream>>>(deg, N, bsum, offsets, cursor);

    // --- fused: layer1 GEMM || edge scatter (independent work, disjoint pipes) ---
    const int scatterBlocks = (E + 255) / 256;
    fused_gemm1_scatter<<<mblocks * 2 + scatterBlocks, 256, 0, stream>>>(
        x, W1, h1, N, ei, E, cursor, csr, mblocks);

    // --- layer 1 rest ---
    att_scores_h2<<<nwave_blocks, 256, 0, stream>>>(h1, att_src1, att_dst1, asrc1, adst1, hpk, N);
    agg_layer1<<<nwave_blocks, 256, 0, stream>>>(hpk, asrc1, adst1, offsets, csr, bias1, out1, N);

    // --- layer 2 ---
    gemm_k128<<<dim3(mblocks, 1), dim3(16, 16), 0, stream>>>(out1, W2, h2, N, 64);
    att_scores_h1<<<nwave_blocks, 256, 0, stream>>>(h2, att_src2, att_dst2, asrc2, adst2, hb, N);
    agg_layer2<<<nwave_blocks, 256, 0, stream>>>(hb, asrc2, adst2, offsets, csr, bias2,
                                                 (float*)d_out, N);
}

// Round 8
// 428.758 us; speedup vs baseline: 1.8229x; 1.0134x over previous
//
#include <hip/hip_runtime.h>
#include <hip/hip_bf16.h>
#include <cstdint>
#include <cstddef>

#define LEAKY(x) ((x) > 0.f ? (x) : 0.2f * (x))

#define NBUCK 128          // buckets of 1024 nodes (N=100000 -> 98 used)
#define BSH   10           // bucket shift
#define BPAD  16           // pad counters to one 64B line apart

__device__ __forceinline__ float readlane_f(float v, int l) {
    return __int_as_float(__builtin_amdgcn_readlane(__float_as_int(v), l));
}
// round-to-nearest-even fp32 -> bf16 bits
__device__ __forceinline__ unsigned short f2bf(float f) {
    unsigned x = __float_as_uint(f);
    return (unsigned short)((x + 0x7fffu + ((x >> 16) & 1u)) >> 16);
}
__device__ __forceinline__ float bf_lo(unsigned u) { return __uint_as_float(u << 16); }
__device__ __forceinline__ float bf_hi(unsigned u) { return __uint_as_float(u & 0xffff0000u); }

// ---------------------------------------------------------------- CSR build
// node-degree histogram + bucket histogram (LDS-aggregated)
__global__ void hist_dst(const int* __restrict__ ei, int E, int* __restrict__ deg,
                         int* __restrict__ bcnt, int nblocks) {
    __shared__ int bl[NBUCK];
    for (int i = threadIdx.x; i < NBUCK; i += 256) bl[i] = 0;
    __syncthreads();
    const int stride = nblocks * 256;
    for (int e = blockIdx.x * 256 + threadIdx.x; e < E; e += stride) {
        int d = ei[E + e];
        atomicAdd(&deg[d], 1);
        atomicAdd(&bl[d >> BSH], 1);
    }
    __syncthreads();
    for (int i = threadIdx.x; i < NBUCK; i += 256) {
        int c = bl[i];
        if (c) atomicAdd(&bcnt[i * BPAD], c);
    }
}

__global__ void scan_phase1(const int* __restrict__ deg, int n, int* __restrict__ bsum) {
    __shared__ int red[256];
    int t = threadIdx.x;
    int base = blockIdx.x * 2048;
    int s = 0;
#pragma unroll
    for (int i = 0; i < 8; ++i) {
        int idx = base + t * 8 + i;
        s += (idx < n) ? deg[idx] : 0;
    }
    red[t] = s;
    __syncthreads();
    for (int o = 128; o > 0; o >>= 1) {
        if (t < o) red[t] += red[t + o];
        __syncthreads();
    }
    if (t == 0) bsum[blockIdx.x] = red[0];
}

// block-sum scan + bucket scan
__global__ void scan_phase2(int* __restrict__ bsum, int nb, int* __restrict__ offsets, int n,
                            const int* __restrict__ bcnt, int* __restrict__ bcur) {
    if (threadIdx.x == 0 && blockIdx.x == 0) {
        int run = 0;
        for (int i = 0; i < nb; ++i) {
            int v = bsum[i];
            bsum[i] = run;
            run += v;
        }
        offsets[n] = run;
        int runb = 0;
        for (int b = 0; b < NBUCK; ++b) {
            int v = bcnt[b * BPAD];
            bcur[b * BPAD] = runb;
            runb += v;
        }
    }
}

// writes both offsets and cursor (cursor = working copy for pass2)
__global__ void scan_phase3(const int* __restrict__ deg, int n, const int* __restrict__ bsum,
                            int* __restrict__ out, int* __restrict__ cursor) {
    __shared__ int sh[256];
    int t = threadIdx.x;
    int base = blockIdx.x * 2048;
    int loc[8];
    int s = 0;
#pragma unroll
    for (int i = 0; i < 8; ++i) {
        int idx = base + t * 8 + i;
        loc[i] = (idx < n) ? deg[idx] : 0;
        s += loc[i];
    }
    sh[t] = s;
    __syncthreads();
    for (int o = 1; o < 256; o <<= 1) {
        int add = (t >= o) ? sh[t - o] : 0;
        __syncthreads();
        sh[t] += add;
        __syncthreads();
    }
    int excl = sh[t] - s + bsum[blockIdx.x];
#pragma unroll
    for (int i = 0; i < 8; ++i) {
        int idx = base + t * 8 + i;
        if (idx < n) {
            out[idx] = excl;
            cursor[idx] = excl;
        }
        excl += loc[i];
    }
}

// ---------------------------------------------------------------- fused: pass1 (edge binning) + GEMM1
// Blocks [0, p1Blocks): bin edges into 128 dst-range buckets (block-aggregated reserve).
// Blocks [p1Blocks, ...): 64x64 GEMM tiles of C[M,128] = A[M,128]@B[128,128].
__global__ __launch_bounds__(256) void fused_gemm1_pass1(
    const float* __restrict__ A, const float* __restrict__ B, float* __restrict__ C, int M,
    const int* __restrict__ ei, int E, int* __restrict__ bcur, int2* __restrict__ ebuf,
    int p1Blocks, int mblocks) {
    __shared__ float As[16][68];
    __shared__ float Bs[16][68];
    __shared__ int bcnt_l[NBUCK];
    __shared__ int bbase_l[NBUCK];
    const int tid = threadIdx.x;
    if ((int)blockIdx.x < p1Blocks) {
        // ---- pass1: bin one 4096-edge chunk
        const int e0 = (int)blockIdx.x * 4096;
        const int ecnt = min(4096, E - e0);
        for (int i = tid; i < NBUCK; i += 256) bcnt_l[i] = 0;
        __syncthreads();
        for (int i = tid; i < ecnt; i += 256) {
            int d = ei[E + e0 + i];
            atomicAdd(&bcnt_l[d >> BSH], 1);
        }
        __syncthreads();
        if (tid < NBUCK) {
            int c = bcnt_l[tid];
            bbase_l[tid] = c ? atomicAdd(&bcur[tid * BPAD], c) : 0;
            bcnt_l[tid] = 0;
        }
        __syncthreads();
        for (int i = tid; i < ecnt; i += 256) {
            int s = ei[e0 + i];
            int d = ei[E + e0 + i];
            int b = d >> BSH;
            int l = atomicAdd(&bcnt_l[b], 1);
            ebuf[bbase_l[b] + l] = make_int2(s, d);
        }
    } else {
        // ---- GEMM tile
        const int gb = (int)blockIdx.x - p1Blocks;
        const int tx = tid & 15, ty = tid >> 4;
        const int by = (gb >= mblocks) ? 1 : 0;
        const int bx = gb - by * mblocks;
        const int row0 = bx * 64;
        const int col0 = by * 64;
        float acc[4][4] = {};
        for (int k0 = 0; k0 < 128; k0 += 16) {
            {
                int idx = tid * 4;
                int r = idx >> 4;
                int c = idx & 15;
                float4 v = make_float4(0.f, 0.f, 0.f, 0.f);
                if (row0 + r < M)
                    v = *(const float4*)(A + (size_t)(row0 + r) * 128 + k0 + c);
                As[c][r] = v.x; As[c + 1][r] = v.y; As[c + 2][r] = v.z; As[c + 3][r] = v.w;
            }
            {
                int idx = tid * 4;
                int r = idx >> 6;
                int c = idx & 63;
                float4 v = *(const float4*)(B + (size_t)(k0 + r) * 128 + col0 + c);
                Bs[r][c] = v.x; Bs[r][c + 1] = v.y; Bs[r][c + 2] = v.z; Bs[r][c + 3] = v.w;
            }
            __syncthreads();
#pragma unroll
            for (int kk = 0; kk < 16; ++kk) {
                float a[4], b[4];
#pragma unroll
                for (int i = 0; i < 4; ++i) a[i] = As[kk][ty * 4 + i];
#pragma unroll
                for (int j = 0; j < 4; ++j) b[j] = Bs[kk][tx * 4 + j];
#pragma unroll
                for (int i = 0; i < 4; ++i)
#pragma unroll
                    for (int j = 0; j < 4; ++j) acc[i][j] += a[i] * b[j];
            }
            __syncthreads();
        }
#pragma unroll
        for (int i = 0; i < 4; ++i) {
            int r = row0 + ty * 4 + i;
            if (r < M) {
#pragma unroll
                for (int j = 0; j < 4; ++j)
                    C[(size_t)r * 128 + col0 + tx * 4 + j] = acc[i][j];
            }
        }
    }
}

// ---------------------------------------------------------------- fused: pass2 (localized scatter) + att_scores_h2
// Blocks [0, p2Blocks): walk ebuf in bucket order -> cursor atomics + csr writes stay in a
// 64KB window per region. Blocks [p2Blocks, ...): attention scores + bf16 pack.
__global__ __launch_bounds__(256) void fused_att2_pass2(
    const int2* __restrict__ ebuf, int E, int* __restrict__ cursor, int* __restrict__ csr,
    const float* __restrict__ h, const float* __restrict__ att_src,
    const float* __restrict__ att_dst, float* __restrict__ asrc, float* __restrict__ adst,
    unsigned* __restrict__ hpk, int N, int p2Blocks) {
    if ((int)blockIdx.x < p2Blocks) {
        const int base = (int)blockIdx.x * 1024;
        const int lim = min(base + 1024, E);
        for (int i = base + (int)threadIdx.x; i < lim; i += 256) {
            int2 p = ebuf[i];
            int pos = atomicAdd(&cursor[p.y], 1);
            csr[pos] = p.x;
        }
    } else {
        int wid = (((int)blockIdx.x - p2Blocks) * 256 + (int)threadIdx.x) >> 6;
        int lane = threadIdx.x & 63;
        if (wid >= N) return;
        const float* row = h + (size_t)wid * 128;
        float h0 = row[lane], h1 = row[64 + lane];
        hpk[(size_t)wid * 64 + lane] = (unsigned)f2bf(h0) | ((unsigned)f2bf(h1) << 16);
        float s0 = h0 * att_src[lane], s1 = h1 * att_src[64 + lane];
        float d0 = h0 * att_dst[lane], d1 = h1 * att_dst[64 + lane];
        for (int m = 32; m > 0; m >>= 1) {
            s0 += __shfl_xor(s0, m);
            s1 += __shfl_xor(s1, m);
            d0 += __shfl_xor(d0, m);
            d1 += __shfl_xor(d1, m);
        }
        if (lane == 0) {
            asrc[wid * 2] = s0; asrc[wid * 2 + 1] = s1;
            adst[wid * 2] = d0; adst[wid * 2 + 1] = d1;
        }
    }
}

// ---------------------------------------------------------------- GEMM (K=128 fixed) for layer 2
__global__ void gemm_k128(const float* __restrict__ A, const float* __restrict__ B,
                          float* __restrict__ C, int M, int Nout) {
    __shared__ float As[16][68];
    __shared__ float Bs[16][68];
    const int tid = threadIdx.y * 16 + threadIdx.x;
    const int row0 = blockIdx.x * 64;
    const int col0 = blockIdx.y * 64;
    float acc[4][4] = {};
    for (int k0 = 0; k0 < 128; k0 += 16) {
        {
            int idx = tid * 4;
            int r = idx >> 4;
            int c = idx & 15;
            float4 v = make_float4(0.f, 0.f, 0.f, 0.f);
            if (row0 + r < M)
                v = *(const float4*)(A + (size_t)(row0 + r) * 128 + k0 + c);
            As[c][r] = v.x; As[c + 1][r] = v.y; As[c + 2][r] = v.z; As[c + 3][r] = v.w;
        }
        {
            int idx = tid * 4;
            int r = idx >> 6;
            int c = idx & 63;
            float4 v = *(const float4*)(B + (size_t)(k0 + r) * Nout + col0 + c);
            Bs[r][c] = v.x; Bs[r][c + 1] = v.y; Bs[r][c + 2] = v.z; Bs[r][c + 3] = v.w;
        }
        __syncthreads();
#pragma unroll
        for (int kk = 0; kk < 16; ++kk) {
            float a[4], b[4];
#pragma unroll
            for (int i = 0; i < 4; ++i) a[i] = As[kk][threadIdx.y * 4 + i];
#pragma unroll
            for (int j = 0; j < 4; ++j) b[j] = Bs[kk][threadIdx.x * 4 + j];
#pragma unroll
            for (int i = 0; i < 4; ++i)
#pragma unroll
                for (int j = 0; j < 4; ++j) acc[i][j] += a[i] * b[j];
        }
        __syncthreads();
    }
#pragma unroll
    for (int i = 0; i < 4; ++i) {
        int r = row0 + threadIdx.y * 4 + i;
        if (r < M) {
#pragma unroll
            for (int j = 0; j < 4; ++j)
                C[(size_t)r * Nout + col0 + threadIdx.x * 4 + j] = acc[i][j];
        }
    }
}

// ---------------------------------------------------------------- attention scores layer2 (+ bf16 pack)
__global__ void att_scores_h1(const float* __restrict__ h, const float* __restrict__ att_src,
                              const float* __restrict__ att_dst, float* __restrict__ asrc,
                              float* __restrict__ adst, unsigned short* __restrict__ hb, int N) {
    int wid = (blockIdx.x * blockDim.x + threadIdx.x) >> 6;
    int lane = threadIdx.x & 63;
    if (wid >= N) return;
    float hv = h[(size_t)wid * 64 + lane];
    hb[(size_t)wid * 64 + lane] = f2bf(hv);
    float s = hv * att_src[lane];
    float d = hv * att_dst[lane];
    for (int m = 32; m > 0; m >>= 1) {
        s += __shfl_xor(s, m);
        d += __shfl_xor(d, m);
    }
    if (lane == 0) {
        asrc[wid] = s;
        adst[wid] = d;
    }
}

// ---------------------------------------------------------------- fused softmax+aggregate
// layer1: ONE wave per node, both heads from one packed uint gather.
__global__ void agg_layer1(const unsigned* __restrict__ hpk, const float* __restrict__ asrc,
                           const float* __restrict__ adst, const int* __restrict__ offs,
                           const int* __restrict__ csr, const float* __restrict__ bias,
                           float* __restrict__ out, int N) {
    int node = (blockIdx.x * blockDim.x + threadIdx.x) >> 6;
    int lane = threadIdx.x & 63;
    if (node >= N) return;
    int off = offs[node], end = offs[node + 1];
    float ad0 = adst[2 * node], ad1 = adst[2 * node + 1];
    float self0 = LEAKY(asrc[2 * node] + ad0);
    float self1 = LEAKY(asrc[2 * node + 1] + ad1);

    // max phase; cache first chunk
    int e0 = off + lane;
    int s_reg = 0;
    float a0_reg = -1e30f, a1_reg = -1e30f;
    if (e0 < end) {
        s_reg = csr[e0];
        float2 as = *(const float2*)&asrc[2 * s_reg];
        a0_reg = LEAKY(as.x + ad0);
        a1_reg = LEAKY(as.y + ad1);
    }
    float m0 = fmaxf(self0, a0_reg), m1 = fmaxf(self1, a1_reg);
    for (int e = off + 64 + lane; e < end; e += 64) {
        int s = csr[e];
        float2 as = *(const float2*)&asrc[2 * s];
        m0 = fmaxf(m0, LEAKY(as.x + ad0));
        m1 = fmaxf(m1, LEAKY(as.y + ad1));
    }
#pragma unroll
    for (int o = 32; o > 0; o >>= 1) {
        m0 = fmaxf(m0, __shfl_xor(m0, o));
        m1 = fmaxf(m1, __shfl_xor(m1, o));
    }

    float sum0, sum1, acc0, acc1;
    {
        unsigned u = hpk[(size_t)node * 64 + lane];
        float ws0 = __expf(self0 - m0), ws1 = __expf(self1 - m1);
        sum0 = ws0; sum1 = ws1;
        acc0 = ws0 * bf_lo(u);
        acc1 = ws1 * bf_hi(u);
    }

    for (int chunk = off; chunk < end; chunk += 64) {
        float w0, w1;
        int s;
        if (chunk == off) {
            s = s_reg;
            bool v = e0 < end;
            w0 = v ? __expf(a0_reg - m0) : 0.f;
            w1 = v ? __expf(a1_reg - m1) : 0.f;
        } else {
            int e = chunk + lane;
            s = 0;
            w0 = 0.f; w1 = 0.f;
            if (e < end) {
                s = csr[e];
                float2 as = *(const float2*)&asrc[2 * s];
                w0 = __expf(LEAKY(as.x + ad0) - m0);
                w1 = __expf(LEAKY(as.y + ad1) - m1);
            }
        }
        float t0 = w0, t1 = w1;
#pragma unroll
        for (int o = 32; o > 0; o >>= 1) {
            t0 += __shfl_xor(t0, o);
            t1 += __shfl_xor(t1, o);
        }
        sum0 += t0; sum1 += t1;

        int cnt = min(64, end - chunk);
        int j = 0;
        for (; j + 4 <= cnt; j += 4) {
            int   sj0 = __builtin_amdgcn_readlane(s, j);
            int   sj1 = __builtin_amdgcn_readlane(s, j + 1);
            int   sj2 = __builtin_amdgcn_readlane(s, j + 2);
            int   sj3 = __builtin_amdgcn_readlane(s, j + 3);
            float p0 = readlane_f(w0, j),     q0 = readlane_f(w1, j);
            float p1 = readlane_f(w0, j + 1), q1 = readlane_f(w1, j + 1);
            float p2 = readlane_f(w0, j + 2), q2 = readlane_f(w1, j + 2);
            float p3 = readlane_f(w0, j + 3), q3 = readlane_f(w1, j + 3);
            unsigned u0 = hpk[(size_t)sj0 * 64 + lane];
            unsigned u1 = hpk[(size_t)sj1 * 64 + lane];
            unsigned u2 = hpk[(size_t)sj2 * 64 + lane];
            unsigned u3 = hpk[(size_t)sj3 * 64 + lane];
            acc0 = fmaf(p0, bf_lo(u0), acc0); acc1 = fmaf(q0, bf_hi(u0), acc1);
            acc0 = fmaf(p1, bf_lo(u1), acc0); acc1 = fmaf(q1, bf_hi(u1), acc1);
            acc0 = fmaf(p2, bf_lo(u2), acc0); acc1 = fmaf(q2, bf_hi(u2), acc1);
            acc0 = fmaf(p3, bf_lo(u3), acc0); acc1 = fmaf(q3, bf_hi(u3), acc1);
        }
        for (; j < cnt; ++j) {
            int   sj = __builtin_amdgcn_readlane(s, j);
            float p = readlane_f(w0, j), q = readlane_f(w1, j);
            unsigned u = hpk[(size_t)sj * 64 + lane];
            acc0 = fmaf(p, bf_lo(u), acc0);
            acc1 = fmaf(q, bf_hi(u), acc1);
        }
    }
    float o0 = acc0 / (sum0 + 1e-16f) + bias[lane];
    float o1 = acc1 / (sum1 + 1e-16f) + bias[64 + lane];
    out[(size_t)node * 128 + lane] = fmaxf(o0, 0.f);
    out[(size_t)node * 128 + 64 + lane] = fmaxf(o1, 0.f);
}

// layer2: one wave per node, bf16 gather, no relu
__global__ void agg_layer2(const unsigned short* __restrict__ hb, const float* __restrict__ asrc,
                           const float* __restrict__ adst, const int* __restrict__ offs,
                           const int* __restrict__ csr, const float* __restrict__ bias,
                           float* __restrict__ out, int N) {
    int node = (blockIdx.x * blockDim.x + threadIdx.x) >> 6;
    int lane = threadIdx.x & 63;
    if (node >= N) return;
    int off = offs[node], end = offs[node + 1];
    float ad = adst[node];
    float self = LEAKY(asrc[node] + ad);

    int e0 = off + lane;
    int s_reg = 0;
    float a_reg = -1e30f;
    if (e0 < end) {
        s_reg = csr[e0];
        a_reg = LEAKY(asrc[s_reg] + ad);
    }
    float m = fmaxf(self, a_reg);
    for (int e = off + 64 + lane; e < end; e += 64) {
        m = fmaxf(m, LEAKY(asrc[csr[e]] + ad));
    }
#pragma unroll
    for (int o = 32; o > 0; o >>= 1) m = fmaxf(m, __shfl_xor(m, o));

    float wself = __expf(self - m);
    float sum = wself;
    float acc = wself * __uint_as_float((unsigned)hb[(size_t)node * 64 + lane] << 16);

    for (int chunk = off; chunk < end; chunk += 64) {
        float w;
        int s;
        if (chunk == off) {
            s = s_reg;
            w = (e0 < end) ? __expf(a_reg - m) : 0.f;
        } else {
            int e = chunk + lane;
            s = 0;
            w = 0.f;
            if (e < end) {
                s = csr[e];
                w = __expf(LEAKY(asrc[s] + ad) - m);
            }
        }
        float t = w;
#pragma unroll
        for (int o = 32; o > 0; o >>= 1) t += __shfl_xor(t, o);
        sum += t;

        int cnt = min(64, end - chunk);
        int j = 0;
        for (; j + 4 <= cnt; j += 4) {
            int   sj0 = __builtin_amdgcn_readlane(s, j);
            int   sj1 = __builtin_amdgcn_readlane(s, j + 1);
            int   sj2 = __builtin_amdgcn_readlane(s, j + 2);
            int   sj3 = __builtin_amdgcn_readlane(s, j + 3);
            float p0 = readlane_f(w, j);
            float p1 = readlane_f(w, j + 1);
            float p2 = readlane_f(w, j + 2);
            float p3 = readlane_f(w, j + 3);
            float v0 = __uint_as_float((unsigned)hb[(size_t)sj0 * 64 + lane] << 16);
            float v1 = __uint_as_float((unsigned)hb[(size_t)sj1 * 64 + lane] << 16);
            float v2 = __uint_as_float((unsigned)hb[(size_t)sj2 * 64 + lane] << 16);
            float v3 = __uint_as_float((unsigned)hb[(size_t)sj3 * 64 + lane] << 16);
            acc = fmaf(p0, v0, acc);
            acc = fmaf(p1, v1, acc);
            acc = fmaf(p2, v2, acc);
            acc = fmaf(p3, v3, acc);
        }
        for (; j < cnt; ++j) {
            int   sj = __builtin_amdgcn_readlane(s, j);
            float p = readlane_f(w, j);
            acc = fmaf(p, __uint_as_float((unsigned)hb[(size_t)sj * 64 + lane] << 16), acc);
        }
    }
    out[(size_t)node * 64 + lane] = acc / (sum + 1e-16f) + bias[lane];
}

// ---------------------------------------------------------------- host
extern "C" void kernel_launch(void* const* d_in, const int* in_sizes, int n_in,
                              void* d_out, int out_size, void* d_ws, size_t ws_size,
                              hipStream_t stream) {
    const float* x        = (const float*)d_in[0];
    const int* ei         = (const int*)d_in[1];
    const float* W1       = (const float*)d_in[2];
    const float* att_src1 = (const float*)d_in[3];
    const float* att_dst1 = (const float*)d_in[4];
    const float* bias1    = (const float*)d_in[5];
    const float* W2       = (const float*)d_in[6];
    const float* att_src2 = (const float*)d_in[7];
    const float* att_dst2 = (const float*)d_in[8];
    const float* bias2    = (const float*)d_in[9];

    const int N = in_sizes[0] / 128;  // 100000
    const int E = in_sizes[1] / 2;    // 1600000

    char* base = (char*)d_ws;
    size_t off = 0;
    auto alloc = [&](size_t bytes) {
        char* p = base + off;
        off = (off + bytes + 255) & ~(size_t)255;
        return p;
    };
    int*      deg     = (int*)alloc((size_t)N * 4);
    int*      bcnt    = (int*)alloc((size_t)NBUCK * BPAD * 4);  // zeroed with deg (adjacent)
    int*      offsets = (int*)alloc((size_t)(N + 1) * 4);
    int*      cursor  = (int*)alloc((size_t)N * 4);
    int*      bsum    = (int*)alloc(4096);
    int*      bcur    = (int*)alloc((size_t)NBUCK * BPAD * 4);
    int*      csr     = (int*)alloc((size_t)E * 4);
    int2*     ebuf    = (int2*)alloc((size_t)E * 8);
    float*    h1      = (float*)alloc((size_t)N * 128 * 4);   // layer1 features (fp32)
    float*    out1    = (float*)alloc((size_t)N * 128 * 4);   // layer1 output / layer2 GEMM input
    unsigned* hpk     = (unsigned*)alloc((size_t)N * 64 * 4); // packed bf16 pairs, layer1
    unsigned short* hb = (unsigned short*)alloc((size_t)N * 64 * 2); // bf16, layer2
    float*    asrc1   = (float*)alloc((size_t)N * 2 * 4);
    float*    adst1   = (float*)alloc((size_t)N * 2 * 4);
    float*    asrc2   = (float*)alloc((size_t)N * 4);
    float*    adst2   = (float*)alloc((size_t)N * 4);
    float*    h2      = h1;  // fp32 layer2 features alias (h1 dead after layer1 agg)

    const int nb = (N + 2047) / 2048;
    const int mblocks = (N + 63) / 64;
    const int nwave_blocks = (N + 3) / 4;
    const int histBlocks = (E + 4095) / 4096;   // 391
    const int p1Blocks = (E + 4095) / 4096;     // 391
    const int p2Blocks = (E + 1023) / 1024;     // 1563

    // --- CSR prefix ---
    hipMemsetAsync(deg, 0, (size_t)N * 4 + (size_t)NBUCK * BPAD * 4 + 256, stream);
    hist_dst<<<histBlocks, 256, 0, stream>>>(ei, E, deg, bcnt, histBlocks);
    scan_phase1<<<nb, 256, 0, stream>>>(deg, N, bsum);
    scan_phase2<<<1, 64, 0, stream>>>(bsum, nb, offsets, N, bcnt, bcur);
    scan_phase3<<<nb, 256, 0, stream>>>(deg, N, bsum, offsets, cursor);

    // --- K1: layer1 GEMM || pass1 edge binning ---
    fused_gemm1_pass1<<<p1Blocks + mblocks * 2, 256, 0, stream>>>(
        x, W1, h1, N, ei, E, bcur, ebuf, p1Blocks, mblocks);

    // --- K2: att scores layer1 || pass2 localized scatter ---
    fused_att2_pass2<<<p2Blocks + nwave_blocks, 256, 0, stream>>>(
        ebuf, E, cursor, csr, h1, att_src1, att_dst1, asrc1, adst1, hpk, N, p2Blocks);

    // --- layer 1 aggregate ---
    agg_layer1<<<nwave_blocks, 256, 0, stream>>>(hpk, asrc1, adst1, offsets, csr, bias1, out1, N);

    // --- layer 2 ---
    gemm_k128<<<dim3(mblocks, 1), dim3(16, 16), 0, stream>>>(out1, W2, h2, N, 64);
    att_scores_h1<<<nwave_blocks, 256, 0, stream>>>(h2, att_src2, att_dst2, asrc2, adst2, hb, N);
    agg_layer2<<<nwave_blocks, 256, 0, stream>>>(hb, asrc2, adst2, offsets, csr, bias2,
                                                 (float*)d_out, N);
}

// Round 9
// 365.486 us; speedup vs baseline: 2.1384x; 1.1731x over previous
//
#include <hip/hip_runtime.h>
#include <hip/hip_bf16.h>
#include <cstdint>
#include <cstddef>

#define LEAKY(x) ((x) > 0.f ? (x) : 0.2f * (x))

#define NBUCK 128          // buckets of 1024 nodes (N=100000 -> 98 used)
#define BSH   10           // bucket shift
#define BPAD  16           // pad counters to one 64B line apart

__device__ __forceinline__ float readlane_f(float v, int l) {
    return __int_as_float(__builtin_amdgcn_readlane(__float_as_int(v), l));
}
// round-to-nearest-even fp32 -> bf16 bits
__device__ __forceinline__ unsigned short f2bf(float f) {
    unsigned x = __float_as_uint(f);
    return (unsigned short)((x + 0x7fffu + ((x >> 16) & 1u)) >> 16);
}
__device__ __forceinline__ float bf_lo(unsigned u) { return __uint_as_float(u << 16); }
__device__ __forceinline__ float bf_hi(unsigned u) { return __uint_as_float(u & 0xffff0000u); }

// ---------------------------------------------------------------- CSR build
// node-degree histogram + bucket histogram (LDS-aggregated)
__global__ void hist_dst(const int* __restrict__ ei, int E, int* __restrict__ deg,
                         int* __restrict__ bcnt, int nblocks) {
    __shared__ int bl[NBUCK];
    for (int i = threadIdx.x; i < NBUCK; i += 256) bl[i] = 0;
    __syncthreads();
    const int stride = nblocks * 256;
    for (int e = blockIdx.x * 256 + threadIdx.x; e < E; e += stride) {
        int d = ei[E + e];
        atomicAdd(&deg[d], 1);
        atomicAdd(&bl[d >> BSH], 1);
    }
    __syncthreads();
    for (int i = threadIdx.x; i < NBUCK; i += 256) {
        int c = bl[i];
        if (c) atomicAdd(&bcnt[i * BPAD], c);
    }
}

__global__ void scan_phase1(const int* __restrict__ deg, int n, int* __restrict__ bsum) {
    __shared__ int red[256];
    int t = threadIdx.x;
    int base = blockIdx.x * 2048;
    int s = 0;
#pragma unroll
    for (int i = 0; i < 8; ++i) {
        int idx = base + t * 8 + i;
        s += (idx < n) ? deg[idx] : 0;
    }
    red[t] = s;
    __syncthreads();
    for (int o = 128; o > 0; o >>= 1) {
        if (t < o) red[t] += red[t + o];
        __syncthreads();
    }
    if (t == 0) bsum[blockIdx.x] = red[0];
}

// block-sum scan + bucket scan (bcur = pass1 working cursor, bstart = read-only starts)
__global__ void scan_phase2(int* __restrict__ bsum, int nb, int* __restrict__ offsets, int n,
                            const int* __restrict__ bcnt, int* __restrict__ bcur,
                            int* __restrict__ bstart) {
    if (threadIdx.x == 0 && blockIdx.x == 0) {
        int run = 0;
        for (int i = 0; i < nb; ++i) {
            int v = bsum[i];
            bsum[i] = run;
            run += v;
        }
        offsets[n] = run;
        int runb = 0;
        for (int b = 0; b < NBUCK; ++b) {
            int v = bcnt[b * BPAD];
            bcur[b * BPAD] = runb;
            bstart[b] = runb;
            runb += v;
        }
        bstart[NBUCK] = runb;
    }
}

// node-offset scan
__global__ void scan_phase3(const int* __restrict__ deg, int n, const int* __restrict__ bsum,
                            int* __restrict__ out) {
    __shared__ int sh[256];
    int t = threadIdx.x;
    int base = blockIdx.x * 2048;
    int loc[8];
    int s = 0;
#pragma unroll
    for (int i = 0; i < 8; ++i) {
        int idx = base + t * 8 + i;
        loc[i] = (idx < n) ? deg[idx] : 0;
        s += loc[i];
    }
    sh[t] = s;
    __syncthreads();
    for (int o = 1; o < 256; o <<= 1) {
        int add = (t >= o) ? sh[t - o] : 0;
        __syncthreads();
        sh[t] += add;
        __syncthreads();
    }
    int excl = sh[t] - s + bsum[blockIdx.x];
#pragma unroll
    for (int i = 0; i < 8; ++i) {
        int idx = base + t * 8 + i;
        if (idx < n) out[idx] = excl;
        excl += loc[i];
    }
}

// ---------------------------------------------------------------- fused: pass1 (edge binning) + GEMM1
__global__ __launch_bounds__(256) void fused_gemm1_pass1(
    const float* __restrict__ A, const float* __restrict__ B, float* __restrict__ C, int M,
    const int* __restrict__ ei, int E, int* __restrict__ bcur, int2* __restrict__ ebuf,
    int p1Blocks, int mblocks) {
    __shared__ float As[16][68];
    __shared__ float Bs[16][68];
    __shared__ int bcnt_l[NBUCK];
    __shared__ int bbase_l[NBUCK];
    const int tid = threadIdx.x;
    if ((int)blockIdx.x < p1Blocks) {
        // ---- pass1: bin one 4096-edge chunk
        const int e0 = (int)blockIdx.x * 4096;
        const int ecnt = min(4096, E - e0);
        for (int i = tid; i < NBUCK; i += 256) bcnt_l[i] = 0;
        __syncthreads();
        for (int i = tid; i < ecnt; i += 256) {
            int d = ei[E + e0 + i];
            atomicAdd(&bcnt_l[d >> BSH], 1);
        }
        __syncthreads();
        if (tid < NBUCK) {
            int c = bcnt_l[tid];
            bbase_l[tid] = c ? atomicAdd(&bcur[tid * BPAD], c) : 0;
            bcnt_l[tid] = 0;
        }
        __syncthreads();
        for (int i = tid; i < ecnt; i += 256) {
            int s = ei[e0 + i];
            int d = ei[E + e0 + i];
            int b = d >> BSH;
            int l = atomicAdd(&bcnt_l[b], 1);
            ebuf[bbase_l[b] + l] = make_int2(s, d);
        }
    } else {
        // ---- GEMM tile
        const int gb = (int)blockIdx.x - p1Blocks;
        const int tx = tid & 15, ty = tid >> 4;
        const int by = (gb >= mblocks) ? 1 : 0;
        const int bx = gb - by * mblocks;
        const int row0 = bx * 64;
        const int col0 = by * 64;
        float acc[4][4] = {};
        for (int k0 = 0; k0 < 128; k0 += 16) {
            {
                int idx = tid * 4;
                int r = idx >> 4;
                int c = idx & 15;
                float4 v = make_float4(0.f, 0.f, 0.f, 0.f);
                if (row0 + r < M)
                    v = *(const float4*)(A + (size_t)(row0 + r) * 128 + k0 + c);
                As[c][r] = v.x; As[c + 1][r] = v.y; As[c + 2][r] = v.z; As[c + 3][r] = v.w;
            }
            {
                int idx = tid * 4;
                int r = idx >> 6;
                int c = idx & 63;
                float4 v = *(const float4*)(B + (size_t)(k0 + r) * 128 + col0 + c);
                Bs[r][c] = v.x; Bs[r][c + 1] = v.y; Bs[r][c + 2] = v.z; Bs[r][c + 3] = v.w;
            }
            __syncthreads();
#pragma unroll
            for (int kk = 0; kk < 16; ++kk) {
                float a[4], b[4];
#pragma unroll
                for (int i = 0; i < 4; ++i) a[i] = As[kk][ty * 4 + i];
#pragma unroll
                for (int j = 0; j < 4; ++j) b[j] = Bs[kk][tx * 4 + j];
#pragma unroll
                for (int i = 0; i < 4; ++i)
#pragma unroll
                    for (int j = 0; j < 4; ++j) acc[i][j] += a[i] * b[j];
            }
            __syncthreads();
        }
#pragma unroll
        for (int i = 0; i < 4; ++i) {
            int r = row0 + ty * 4 + i;
            if (r < M) {
#pragma unroll
                for (int j = 0; j < 4; ++j)
                    C[(size_t)r * 128 + col0 + tx * 4 + j] = acc[i][j];
            }
        }
    }
}

// ---------------------------------------------------------------- fused: pass2 (bucket-local scatter, LDS cursor) + att_scores_h2
// Blocks [0, nbuckets): ONE block per bucket. Cursor in LDS; csr writes confined to this
// block's private ~64KB window on one XCD -> each line written back once.
// Blocks [nbuckets, ...): attention scores + bf16 pack.
__global__ __launch_bounds__(256) void fused_att2_pass2(
    const int2* __restrict__ ebuf, const int* __restrict__ bstart,
    const int* __restrict__ offsets, int* __restrict__ csr,
    const float* __restrict__ h, const float* __restrict__ att_src,
    const float* __restrict__ att_dst, float* __restrict__ asrc, float* __restrict__ adst,
    unsigned* __restrict__ hpk, int N, int nbuckets) {
    __shared__ int lcur[1 << BSH];
    if ((int)blockIdx.x < nbuckets) {
        const int b = (int)blockIdx.x;
        const int dbase = b << BSH;
        const int ncnt = min(1 << BSH, N - dbase);
        for (int i = threadIdx.x; i < ncnt; i += 256) lcur[i] = offsets[dbase + i];
        __syncthreads();
        const int es = bstart[b], ee = bstart[b + 1];
        for (int i = es + (int)threadIdx.x; i < ee; i += 256) {
            int2 p = ebuf[i];
            int pos = atomicAdd(&lcur[p.y - dbase], 1);
            csr[pos] = p.x;
        }
    } else {
        int wid = (((int)blockIdx.x - nbuckets) * 256 + (int)threadIdx.x) >> 6;
        int lane = threadIdx.x & 63;
        if (wid >= N) return;
        const float* row = h + (size_t)wid * 128;
        float h0 = row[lane], h1 = row[64 + lane];
        hpk[(size_t)wid * 64 + lane] = (unsigned)f2bf(h0) | ((unsigned)f2bf(h1) << 16);
        float s0 = h0 * att_src[lane], s1 = h1 * att_src[64 + lane];
        float d0 = h0 * att_dst[lane], d1 = h1 * att_dst[64 + lane];
        for (int m = 32; m > 0; m >>= 1) {
            s0 += __shfl_xor(s0, m);
            s1 += __shfl_xor(s1, m);
            d0 += __shfl_xor(d0, m);
            d1 += __shfl_xor(d1, m);
        }
        if (lane == 0) {
            asrc[wid * 2] = s0; asrc[wid * 2 + 1] = s1;
            adst[wid * 2] = d0; adst[wid * 2 + 1] = d1;
        }
    }
}

// ---------------------------------------------------------------- GEMM (K=128 fixed) for layer 2
__global__ void gemm_k128(const float* __restrict__ A, const float* __restrict__ B,
                          float* __restrict__ C, int M, int Nout) {
    __shared__ float As[16][68];
    __shared__ float Bs[16][68];
    const int tid = threadIdx.y * 16 + threadIdx.x;
    const int row0 = blockIdx.x * 64;
    const int col0 = blockIdx.y * 64;
    float acc[4][4] = {};
    for (int k0 = 0; k0 < 128; k0 += 16) {
        {
            int idx = tid * 4;
            int r = idx >> 4;
            int c = idx & 15;
            float4 v = make_float4(0.f, 0.f, 0.f, 0.f);
            if (row0 + r < M)
                v = *(const float4*)(A + (size_t)(row0 + r) * 128 + k0 + c);
            As[c][r] = v.x; As[c + 1][r] = v.y; As[c + 2][r] = v.z; As[c + 3][r] = v.w;
        }
        {
            int idx = tid * 4;
            int r = idx >> 6;
            int c = idx & 63;
            float4 v = *(const float4*)(B + (size_t)(k0 + r) * Nout + col0 + c);
            Bs[r][c] = v.x; Bs[r][c + 1] = v.y; Bs[r][c + 2] = v.z; Bs[r][c + 3] = v.w;
        }
        __syncthreads();
#pragma unroll
        for (int kk = 0; kk < 16; ++kk) {
            float a[4], b[4];
#pragma unroll
            for (int i = 0; i < 4; ++i) a[i] = As[kk][threadIdx.y * 4 + i];
#pragma unroll
            for (int j = 0; j < 4; ++j) b[j] = Bs[kk][threadIdx.x * 4 + j];
#pragma unroll
            for (int i = 0; i < 4; ++i)
#pragma unroll
                for (int j = 0; j < 4; ++j) acc[i][j] += a[i] * b[j];
        }
        __syncthreads();
    }
#pragma unroll
    for (int i = 0; i < 4; ++i) {
        int r = row0 + threadIdx.y * 4 + i;
        if (r < M) {
#pragma unroll
            for (int j = 0; j < 4; ++j)
                C[(size_t)r * Nout + col0 + threadIdx.x * 4 + j] = acc[i][j];
        }
    }
}

// ---------------------------------------------------------------- attention scores layer2 (+ bf16 pack)
__global__ void att_scores_h1(const float* __restrict__ h, const float* __restrict__ att_src,
                              const float* __restrict__ att_dst, float* __restrict__ asrc,
                              float* __restrict__ adst, unsigned short* __restrict__ hb, int N) {
    int wid = (blockIdx.x * blockDim.x + threadIdx.x) >> 6;
    int lane = threadIdx.x & 63;
    if (wid >= N) return;
    float hv = h[(size_t)wid * 64 + lane];
    hb[(size_t)wid * 64 + lane] = f2bf(hv);
    float s = hv * att_src[lane];
    float d = hv * att_dst[lane];
    for (int m = 32; m > 0; m >>= 1) {
        s += __shfl_xor(s, m);
        d += __shfl_xor(d, m);
    }
    if (lane == 0) {
        asrc[wid] = s;
        adst[wid] = d;
    }
}

// ---------------------------------------------------------------- fused softmax+aggregate
// layer1: ONE wave per node, both heads from one packed uint gather.
__global__ void agg_layer1(const unsigned* __restrict__ hpk, const float* __restrict__ asrc,
                           const float* __restrict__ adst, const int* __restrict__ offs,
                           const int* __restrict__ csr, const float* __restrict__ bias,
                           float* __restrict__ out, int N) {
    int node = (blockIdx.x * blockDim.x + threadIdx.x) >> 6;
    int lane = threadIdx.x & 63;
    if (node >= N) return;
    int off = offs[node], end = offs[node + 1];
    float ad0 = adst[2 * node], ad1 = adst[2 * node + 1];
    float self0 = LEAKY(asrc[2 * node] + ad0);
    float self1 = LEAKY(asrc[2 * node + 1] + ad1);

    // max phase; cache first chunk
    int e0 = off + lane;
    int s_reg = 0;
    float a0_reg = -1e30f, a1_reg = -1e30f;
    if (e0 < end) {
        s_reg = csr[e0];
        float2 as = *(const float2*)&asrc[2 * s_reg];
        a0_reg = LEAKY(as.x + ad0);
        a1_reg = LEAKY(as.y + ad1);
    }
    float m0 = fmaxf(self0, a0_reg), m1 = fmaxf(self1, a1_reg);
    for (int e = off + 64 + lane; e < end; e += 64) {
        int s = csr[e];
        float2 as = *(const float2*)&asrc[2 * s];
        m0 = fmaxf(m0, LEAKY(as.x + ad0));
        m1 = fmaxf(m1, LEAKY(as.y + ad1));
    }
#pragma unroll
    for (int o = 32; o > 0; o >>= 1) {
        m0 = fmaxf(m0, __shfl_xor(m0, o));
        m1 = fmaxf(m1, __shfl_xor(m1, o));
    }

    float sum0, sum1, acc0, acc1;
    {
        unsigned u = hpk[(size_t)node * 64 + lane];
        float ws0 = __expf(self0 - m0), ws1 = __expf(self1 - m1);
        sum0 = ws0; sum1 = ws1;
        acc0 = ws0 * bf_lo(u);
        acc1 = ws1 * bf_hi(u);
    }

    for (int chunk = off; chunk < end; chunk += 64) {
        float w0, w1;
        int s;
        if (chunk == off) {
            s = s_reg;
            bool v = e0 < end;
            w0 = v ? __expf(a0_reg - m0) : 0.f;
            w1 = v ? __expf(a1_reg - m1) : 0.f;
        } else {
            int e = chunk + lane;
            s = 0;
            w0 = 0.f; w1 = 0.f;
            if (e < end) {
                s = csr[e];
                float2 as = *(const float2*)&asrc[2 * s];
                w0 = __expf(LEAKY(as.x + ad0) - m0);
                w1 = __expf(LEAKY(as.y + ad1) - m1);
            }
        }
        float t0 = w0, t1 = w1;
#pragma unroll
        for (int o = 32; o > 0; o >>= 1) {
            t0 += __shfl_xor(t0, o);
            t1 += __shfl_xor(t1, o);
        }
        sum0 += t0; sum1 += t1;

        int cnt = min(64, end - chunk);
        int j = 0;
        for (; j + 4 <= cnt; j += 4) {
            int   sj0 = __builtin_amdgcn_readlane(s, j);
            int   sj1 = __builtin_amdgcn_readlane(s, j + 1);
            int   sj2 = __builtin_amdgcn_readlane(s, j + 2);
            int   sj3 = __builtin_amdgcn_readlane(s, j + 3);
            float p0 = readlane_f(w0, j),     q0 = readlane_f(w1, j);
            float p1 = readlane_f(w0, j + 1), q1 = readlane_f(w1, j + 1);
            float p2 = readlane_f(w0, j + 2), q2 = readlane_f(w1, j + 2);
            float p3 = readlane_f(w0, j + 3), q3 = readlane_f(w1, j + 3);
            unsigned u0 = hpk[(size_t)sj0 * 64 + lane];
            unsigned u1 = hpk[(size_t)sj1 * 64 + lane];
            unsigned u2 = hpk[(size_t)sj2 * 64 + lane];
            unsigned u3 = hpk[(size_t)sj3 * 64 + lane];
            acc0 = fmaf(p0, bf_lo(u0), acc0); acc1 = fmaf(q0, bf_hi(u0), acc1);
            acc0 = fmaf(p1, bf_lo(u1), acc0); acc1 = fmaf(q1, bf_hi(u1), acc1);
            acc0 = fmaf(p2, bf_lo(u2), acc0); acc1 = fmaf(q2, bf_hi(u2), acc1);
            acc0 = fmaf(p3, bf_lo(u3), acc0); acc1 = fmaf(q3, bf_hi(u3), acc1);
        }
        for (; j < cnt; ++j) {
            int   sj = __builtin_amdgcn_readlane(s, j);
            float p = readlane_f(w0, j), q = readlane_f(w1, j);
            unsigned u = hpk[(size_t)sj * 64 + lane];
            acc0 = fmaf(p, bf_lo(u), acc0);
            acc1 = fmaf(q, bf_hi(u), acc1);
        }
    }
    float o0 = acc0 / (sum0 + 1e-16f) + bias[lane];
    float o1 = acc1 / (sum1 + 1e-16f) + bias[64 + lane];
    out[(size_t)node * 128 + lane] = fmaxf(o0, 0.f);
    out[(size_t)node * 128 + 64 + lane] = fmaxf(o1, 0.f);
}

// layer2: one wave per node, bf16 gather, no relu
__global__ void agg_layer2(const unsigned short* __restrict__ hb, const float* __restrict__ asrc,
                           const float* __restrict__ adst, const int* __restrict__ offs,
                           const int* __restrict__ csr, const float* __restrict__ bias,
                           float* __restrict__ out, int N) {
    int node = (blockIdx.x * blockDim.x + threadIdx.x) >> 6;
    int lane = threadIdx.x & 63;
    if (node >= N) return;
    int off = offs[node], end = offs[node + 1];
    float ad = adst[node];
    float self = LEAKY(asrc[node] + ad);

    int e0 = off + lane;
    int s_reg = 0;
    float a_reg = -1e30f;
    if (e0 < end) {
        s_reg = csr[e0];
        a_reg = LEAKY(asrc[s_reg] + ad);
    }
    float m = fmaxf(self, a_reg);
    for (int e = off + 64 + lane; e < end; e += 64) {
        m = fmaxf(m, LEAKY(asrc[csr[e]] + ad));
    }
#pragma unroll
    for (int o = 32; o > 0; o >>= 1) m = fmaxf(m, __shfl_xor(m, o));

    float wself = __expf(self - m);
    float sum = wself;
    float acc = wself * __uint_as_float((unsigned)hb[(size_t)node * 64 + lane] << 16);

    for (int chunk = off; chunk < end; chunk += 64) {
        float w;
        int s;
        if (chunk == off) {
            s = s_reg;
            w = (e0 < end) ? __expf(a_reg - m) : 0.f;
        } else {
            int e = chunk + lane;
            s = 0;
            w = 0.f;
            if (e < end) {
                s = csr[e];
                w = __expf(LEAKY(asrc[s] + ad) - m);
            }
        }
        float t = w;
#pragma unroll
        for (int o = 32; o > 0; o >>= 1) t += __shfl_xor(t, o);
        sum += t;

        int cnt = min(64, end - chunk);
        int j = 0;
        for (; j + 4 <= cnt; j += 4) {
            int   sj0 = __builtin_amdgcn_readlane(s, j);
            int   sj1 = __builtin_amdgcn_readlane(s, j + 1);
            int   sj2 = __builtin_amdgcn_readlane(s, j + 2);
            int   sj3 = __builtin_amdgcn_readlane(s, j + 3);
            float p0 = readlane_f(w, j);
            float p1 = readlane_f(w, j + 1);
            float p2 = readlane_f(w, j + 2);
            float p3 = readlane_f(w, j + 3);
            float v0 = __uint_as_float((unsigned)hb[(size_t)sj0 * 64 + lane] << 16);
            float v1 = __uint_as_float((unsigned)hb[(size_t)sj1 * 64 + lane] << 16);
            float v2 = __uint_as_float((unsigned)hb[(size_t)sj2 * 64 + lane] << 16);
            float v3 = __uint_as_float((unsigned)hb[(size_t)sj3 * 64 + lane] << 16);
            acc = fmaf(p0, v0, acc);
            acc = fmaf(p1, v1, acc);
            acc = fmaf(p2, v2, acc);
            acc = fmaf(p3, v3, acc);
        }
        for (; j < cnt; ++j) {
            int   sj = __builtin_amdgcn_readlane(s, j);
            float p = readlane_f(w, j);
            acc = fmaf(p, __uint_as_float((unsigned)hb[(size_t)sj * 64 + lane] << 16), acc);
        }
    }
    out[(size_t)node * 64 + lane] = acc / (sum + 1e-16f) + bias[lane];
}

// ---------------------------------------------------------------- host
extern "C" void kernel_launch(void* const* d_in, const int* in_sizes, int n_in,
                              void* d_out, int out_size, void* d_ws, size_t ws_size,
                              hipStream_t stream) {
    const float* x        = (const float*)d_in[0];
    const int* ei         = (const int*)d_in[1];
    const float* W1       = (const float*)d_in[2];
    const float* att_src1 = (const float*)d_in[3];
    const float* att_dst1 = (const float*)d_in[4];
    const float* bias1    = (const float*)d_in[5];
    const float* W2       = (const float*)d_in[6];
    const float* att_src2 = (const float*)d_in[7];
    const float* att_dst2 = (const float*)d_in[8];
    const float* bias2    = (const float*)d_in[9];

    const int N = in_sizes[0] / 128;  // 100000
    const int E = in_sizes[1] / 2;    // 1600000

    char* base = (char*)d_ws;
    size_t off = 0;
    auto alloc = [&](size_t bytes) {
        char* p = base + off;
        off = (off + bytes + 255) & ~(size_t)255;
        return p;
    };
    int*      deg     = (int*)alloc((size_t)N * 4);
    int*      bcnt    = (int*)alloc((size_t)NBUCK * BPAD * 4);  // zeroed with deg (adjacent)
    int*      offsets = (int*)alloc((size_t)(N + 1) * 4);
    int*      bsum    = (int*)alloc(4096);
    int*      bcur    = (int*)alloc((size_t)NBUCK * BPAD * 4);
    int*      bstart  = (int*)alloc((size_t)(NBUCK + 1) * 4);
    int*      csr     = (int*)alloc((size_t)E * 4);
    int2*     ebuf    = (int2*)alloc((size_t)E * 8);
    float*    h1      = (float*)alloc((size_t)N * 128 * 4);   // layer1 features (fp32)
    float*    out1    = (float*)alloc((size_t)N * 128 * 4);   // layer1 output / layer2 GEMM input
    unsigned* hpk     = (unsigned*)alloc((size_t)N * 64 * 4); // packed bf16 pairs, layer1
    unsigned short* hb = (unsigned short*)alloc((size_t)N * 64 * 2); // bf16, layer2
    float*    asrc1   = (float*)alloc((size_t)N * 2 * 4);
    float*    adst1   = (float*)alloc((size_t)N * 2 * 4);
    float*    asrc2   = (float*)alloc((size_t)N * 4);
    float*    adst2   = (float*)alloc((size_t)N * 4);
    float*    h2      = h1;  // fp32 layer2 features alias (h1 dead after layer1 agg)

    const int nb = (N + 2047) / 2048;
    const int mblocks = (N + 63) / 64;
    const int nwave_blocks = (N + 3) / 4;
    const int histBlocks = (E + 4095) / 4096;   // 391
    const int p1Blocks = (E + 4095) / 4096;     // 391
    const int nbuckets = (N + (1 << BSH) - 1) >> BSH;  // 98

    // --- CSR prefix ---
    hipMemsetAsync(deg, 0, (size_t)N * 4 + (size_t)NBUCK * BPAD * 4 + 256, stream);
    hist_dst<<<histBlocks, 256, 0, stream>>>(ei, E, deg, bcnt, histBlocks);
    scan_phase1<<<nb, 256, 0, stream>>>(deg, N, bsum);
    scan_phase2<<<1, 64, 0, stream>>>(bsum, nb, offsets, N, bcnt, bcur, bstart);
    scan_phase3<<<nb, 256, 0, stream>>>(deg, N, bsum, offsets);

    // --- K1: layer1 GEMM || pass1 edge binning ---
    fused_gemm1_pass1<<<p1Blocks + mblocks * 2, 256, 0, stream>>>(
        x, W1, h1, N, ei, E, bcur, ebuf, p1Blocks, mblocks);

    // --- K2: att scores layer1 || pass2 bucket-local scatter (LDS cursor) ---
    fused_att2_pass2<<<nbuckets + nwave_blocks, 256, 0, stream>>>(
        ebuf, bstart, offsets, csr, h1, att_src1, att_dst1, asrc1, adst1, hpk, N, nbuckets);

    // --- layer 1 aggregate ---
    agg_layer1<<<nwave_blocks, 256, 0, stream>>>(hpk, asrc1, adst1, offsets, csr, bias1, out1, N);

    // --- layer 2 ---
    gemm_k128<<<dim3(mblocks, 1), dim3(16, 16), 0, stream>>>(out1, W2, h2, N, 64);
    att_scores_h1<<<nwave_blocks, 256, 0, stream>>>(h2, att_src2, att_dst2, asrc2, adst2, hb, N);
    agg_layer2<<<nwave_blocks, 256, 0, stream>>>(hb, asrc2, adst2, offsets, csr, bias2,
                                                 (float*)d_out, N);
}

// Round 10
// 291.634 us; speedup vs baseline: 2.6800x; 1.2532x over previous
//
#include <hip/hip_runtime.h>
#include <hip/hip_bf16.h>
#include <cstdint>
#include <cstddef>

#define LEAKY(x) ((x) > 0.f ? (x) : 0.2f * (x))

#define NBUCK 128          // buckets of 1024 nodes (N=100000 -> 98 used)
#define BSH   10           // bucket shift
#define BPAD  16           // pad counters one 64B line apart

__device__ __forceinline__ float readlane_f(float v, int l) {
    return __int_as_float(__builtin_amdgcn_readlane(__float_as_int(v), l));
}
// round-to-nearest-even fp32 -> bf16 bits
__device__ __forceinline__ unsigned short f2bf(float f) {
    unsigned x = __float_as_uint(f);
    return (unsigned short)((x + 0x7fffu + ((x >> 16) & 1u)) >> 16);
}
__device__ __forceinline__ float bf_lo(unsigned u) { return __uint_as_float(u << 16); }
__device__ __forceinline__ float bf_hi(unsigned u) { return __uint_as_float(u & 0xffff0000u); }

// ---------------------------------------------------------------- bucket histogram (no per-node atomics)
__global__ void hist_bucket(const int* __restrict__ ei, int E, int* __restrict__ bcnt,
                            int nblocks) {
    __shared__ int bl[NBUCK];
    for (int i = threadIdx.x; i < NBUCK; i += 256) bl[i] = 0;
    __syncthreads();
    const int stride = nblocks * 256;
    for (int e = blockIdx.x * 256 + threadIdx.x; e < E; e += stride)
        atomicAdd(&bl[ei[E + e] >> BSH], 1);
    __syncthreads();
    for (int i = threadIdx.x; i < NBUCK; i += 256) {
        int c = bl[i];
        if (c) atomicAdd(&bcnt[i * BPAD], c);
    }
}

// bucket exclusive scan (tiny)
__global__ void scan_bucket(const int* __restrict__ bcnt, int* __restrict__ bcur,
                            int* __restrict__ bstart, int* __restrict__ offsets, int n) {
    if (threadIdx.x == 0 && blockIdx.x == 0) {
        int run = 0;
        for (int b = 0; b < NBUCK; ++b) {
            int v = bcnt[b * BPAD];
            bcur[b * BPAD] = run;
            bstart[b] = run;
            run += v;
        }
        bstart[NBUCK] = run;
        offsets[n] = run;
    }
}

// ---------------------------------------------------------------- K1: pass1 (edge binning) + GEMM1+epilogue
// GEMM blocks: C=A@W1 tile held in regs; epilogue computes att scores (shuffle reduce)
// and writes bf16-packed features. No fp32 h1 is ever written.
__global__ __launch_bounds__(256) void fused_gemm1_pass1(
    const float* __restrict__ A, const float* __restrict__ B, int M,
    const float* __restrict__ att_src, const float* __restrict__ att_dst,
    unsigned short* __restrict__ hpk16, float* __restrict__ asrc, float* __restrict__ adst,
    const int* __restrict__ ei, int E, int* __restrict__ bcur, int2* __restrict__ ebuf,
    int p1Blocks, int mblocks) {
    __shared__ float As[16][68];
    __shared__ float Bs[16][68];
    __shared__ int bcnt_l[NBUCK];
    __shared__ int bbase_l[NBUCK];
    const int tid = threadIdx.x;
    if ((int)blockIdx.x < p1Blocks) {
        // ---- pass1: bin one 4096-edge chunk into dst-range buckets
        const int e0 = (int)blockIdx.x * 4096;
        const int ecnt = min(4096, E - e0);
        for (int i = tid; i < NBUCK; i += 256) bcnt_l[i] = 0;
        __syncthreads();
        for (int i = tid; i < ecnt; i += 256)
            atomicAdd(&bcnt_l[ei[E + e0 + i] >> BSH], 1);
        __syncthreads();
        if (tid < NBUCK) {
            int c = bcnt_l[tid];
            bbase_l[tid] = c ? atomicAdd(&bcur[tid * BPAD], c) : 0;
            bcnt_l[tid] = 0;
        }
        __syncthreads();
        for (int i = tid; i < ecnt; i += 256) {
            int s = ei[e0 + i];
            int d = ei[E + e0 + i];
            int b = d >> BSH;
            int l = atomicAdd(&bcnt_l[b], 1);
            ebuf[bbase_l[b] + l] = make_int2(s, d);
        }
    } else {
        // ---- GEMM tile (64 rows x 64 cols; by = head)
        const int gb = (int)blockIdx.x - p1Blocks;
        const int tx = tid & 15, ty = tid >> 4;
        const int by = (gb >= mblocks) ? 1 : 0;
        const int bx = gb - by * mblocks;
        const int row0 = bx * 64;
        const int col0 = by * 64;
        float acc[4][4] = {};
        for (int k0 = 0; k0 < 128; k0 += 16) {
            {
                int idx = tid * 4;
                int r = idx >> 4;
                int c = idx & 15;
                float4 v = make_float4(0.f, 0.f, 0.f, 0.f);
                if (row0 + r < M)
                    v = *(const float4*)(A + (size_t)(row0 + r) * 128 + k0 + c);
                As[c][r] = v.x; As[c + 1][r] = v.y; As[c + 2][r] = v.z; As[c + 3][r] = v.w;
            }
            {
                int idx = tid * 4;
                int r = idx >> 6;
                int c = idx & 63;
                float4 v = *(const float4*)(B + (size_t)(k0 + r) * 128 + col0 + c);
                Bs[r][c] = v.x; Bs[r][c + 1] = v.y; Bs[r][c + 2] = v.z; Bs[r][c + 3] = v.w;
            }
            __syncthreads();
#pragma unroll
            for (int kk = 0; kk < 16; ++kk) {
                float a[4], b[4];
#pragma unroll
                for (int i = 0; i < 4; ++i) a[i] = As[kk][ty * 4 + i];
#pragma unroll
                for (int j = 0; j < 4; ++j) b[j] = Bs[kk][tx * 4 + j];
#pragma unroll
                for (int i = 0; i < 4; ++i)
#pragma unroll
                    for (int j = 0; j < 4; ++j) acc[i][j] += a[i] * b[j];
            }
            __syncthreads();
        }
        // ---- epilogue: att scores + bf16 pack
        float as_[4], ad_[4];
#pragma unroll
        for (int j = 0; j < 4; ++j) {
            as_[j] = att_src[by * 64 + tx * 4 + j];
            ad_[j] = att_dst[by * 64 + tx * 4 + j];
        }
#pragma unroll
        for (int i = 0; i < 4; ++i) {
            int r = row0 + ty * 4 + i;
            float ps = 0.f, pd = 0.f;
#pragma unroll
            for (int j = 0; j < 4; ++j) {
                ps = fmaf(acc[i][j], as_[j], ps);
                pd = fmaf(acc[i][j], ad_[j], pd);
            }
#pragma unroll
            for (int m = 8; m > 0; m >>= 1) {
                ps += __shfl_xor(ps, m);
                pd += __shfl_xor(pd, m);
            }
            if (r < M) {
                if (tx == 0) { asrc[2 * r + by] = ps; adst[2 * r + by] = pd; }
#pragma unroll
                for (int j = 0; j < 4; ++j)
                    hpk16[((size_t)r * 64 + tx * 4 + j) * 2 + by] = f2bf(acc[i][j]);
            }
        }
    }
}

// ---------------------------------------------------------------- K2: per-bucket offsets + localized scatter
__global__ __launch_bounds__(256) void pass2_build(
    const int2* __restrict__ ebuf, const int* __restrict__ bstart, int* __restrict__ offsets,
    int* __restrict__ csr, int N) {
    __shared__ int lcur[1 << BSH];
    __shared__ int ssum[256];
    const int b = blockIdx.x;
    const int dbase = b << BSH;
    const int tid = threadIdx.x;
    for (int i = tid; i < (1 << BSH); i += 256) lcur[i] = 0;
    __syncthreads();
    const int es = bstart[b], ee = bstart[b + 1];
    for (int i = es + tid; i < ee; i += 256)
        atomicAdd(&lcur[ebuf[i].y - dbase], 1);
    __syncthreads();
    // local exclusive scan of 1024 counts
    const int base_ = tid * 4;
    int v0 = lcur[base_], v1 = lcur[base_ + 1], v2 = lcur[base_ + 2], v3 = lcur[base_ + 3];
    ssum[tid] = v0 + v1 + v2 + v3;
    __syncthreads();
    for (int o = 1; o < 256; o <<= 1) {
        int add = (tid >= o) ? ssum[tid - o] : 0;
        __syncthreads();
        ssum[tid] += add;
        __syncthreads();
    }
    int excl = (tid ? ssum[tid - 1] : 0) + bstart[b];
    int c0 = excl, c1 = c0 + v0, c2 = c1 + v1, c3 = c2 + v2;
    lcur[base_] = c0; lcur[base_ + 1] = c1; lcur[base_ + 2] = c2; lcur[base_ + 3] = c3;
    int idx = dbase + base_;
    if (idx < N)     offsets[idx] = c0;
    if (idx + 1 < N) offsets[idx + 1] = c1;
    if (idx + 2 < N) offsets[idx + 2] = c2;
    if (idx + 3 < N) offsets[idx + 3] = c3;
    __syncthreads();
    for (int i = es + tid; i < ee; i += 256) {
        int2 p = ebuf[i];
        int pos = atomicAdd(&lcur[p.y - dbase], 1);
        csr[pos] = p.x;
    }
}

// ---------------------------------------------------------------- K3: GEMM2 + epilogue (hb, asrc2, adst2)
__global__ __launch_bounds__(256) void gemm2_epi(
    const float* __restrict__ A, const float* __restrict__ B, int M,
    const float* __restrict__ att_src, const float* __restrict__ att_dst,
    unsigned short* __restrict__ hb, float* __restrict__ asrc, float* __restrict__ adst) {
    __shared__ float As[16][68];
    __shared__ float Bs[16][68];
    const int tid = threadIdx.x;
    const int tx = tid & 15, ty = tid >> 4;
    const int row0 = blockIdx.x * 64;
    float acc[4][4] = {};
    for (int k0 = 0; k0 < 128; k0 += 16) {
        {
            int idx = tid * 4;
            int r = idx >> 4;
            int c = idx & 15;
            float4 v = make_float4(0.f, 0.f, 0.f, 0.f);
            if (row0 + r < M)
                v = *(const float4*)(A + (size_t)(row0 + r) * 128 + k0 + c);
            As[c][r] = v.x; As[c + 1][r] = v.y; As[c + 2][r] = v.z; As[c + 3][r] = v.w;
        }
        {
            int idx = tid * 4;
            int r = idx >> 6;
            int c = idx & 63;
            float4 v = *(const float4*)(B + (size_t)(k0 + r) * 64 + c);
            Bs[r][c] = v.x; Bs[r][c + 1] = v.y; Bs[r][c + 2] = v.z; Bs[r][c + 3] = v.w;
        }
        __syncthreads();
#pragma unroll
        for (int kk = 0; kk < 16; ++kk) {
            float a[4], bb[4];
#pragma unroll
            for (int i = 0; i < 4; ++i) a[i] = As[kk][ty * 4 + i];
#pragma unroll
            for (int j = 0; j < 4; ++j) bb[j] = Bs[kk][tx * 4 + j];
#pragma unroll
            for (int i = 0; i < 4; ++i)
#pragma unroll
                for (int j = 0; j < 4; ++j) acc[i][j] += a[i] * bb[j];
        }
        __syncthreads();
    }
    float as_[4], ad_[4];
#pragma unroll
    for (int j = 0; j < 4; ++j) {
        as_[j] = att_src[tx * 4 + j];
        ad_[j] = att_dst[tx * 4 + j];
    }
#pragma unroll
    for (int i = 0; i < 4; ++i) {
        int r = row0 + ty * 4 + i;
        float ps = 0.f, pd = 0.f;
#pragma unroll
        for (int j = 0; j < 4; ++j) {
            ps = fmaf(acc[i][j], as_[j], ps);
            pd = fmaf(acc[i][j], ad_[j], pd);
        }
#pragma unroll
        for (int m = 8; m > 0; m >>= 1) {
            ps += __shfl_xor(ps, m);
            pd += __shfl_xor(pd, m);
        }
        if (r < M) {
            if (tx == 0) { asrc[r] = ps; adst[r] = pd; }
#pragma unroll
            for (int j = 0; j < 4; ++j)
                hb[(size_t)r * 64 + tx * 4 + j] = f2bf(acc[i][j]);
        }
    }
}

// ---------------------------------------------------------------- agg layer1: no-max softmax + aggregate
__global__ void agg_layer1(const unsigned* __restrict__ hpk, const float* __restrict__ asrc,
                           const float* __restrict__ adst, const int* __restrict__ offs,
                           const int* __restrict__ csr, const float* __restrict__ bias,
                           float* __restrict__ out, int N) {
    int node = (blockIdx.x * blockDim.x + threadIdx.x) >> 6;
    int lane = threadIdx.x & 63;
    if (node >= N) return;
    int off = offs[node], end = offs[node + 1];
    float ad0 = adst[2 * node], ad1 = adst[2 * node + 1];
    float ws0 = __expf(fminf(LEAKY(asrc[2 * node] + ad0), 60.f));
    float ws1 = __expf(fminf(LEAKY(asrc[2 * node + 1] + ad1), 60.f));
    float sum0 = ws0, sum1 = ws1;
    float acc0, acc1;
    {
        unsigned u = hpk[(size_t)node * 64 + lane];
        acc0 = ws0 * bf_lo(u);
        acc1 = ws1 * bf_hi(u);
    }
    for (int chunk = off; chunk < end; chunk += 64) {
        int e = chunk + lane;
        int s = 0;
        float w0 = 0.f, w1 = 0.f;
        if (e < end) {
            s = csr[e];
            float2 as = *(const float2*)&asrc[2 * s];
            w0 = __expf(fminf(LEAKY(as.x + ad0), 60.f));
            w1 = __expf(fminf(LEAKY(as.y + ad1), 60.f));
        }
        float t0 = w0, t1 = w1;
#pragma unroll
        for (int o = 32; o > 0; o >>= 1) {
            t0 += __shfl_xor(t0, o);
            t1 += __shfl_xor(t1, o);
        }
        sum0 += t0; sum1 += t1;

        int cnt = min(64, end - chunk);
        int j = 0;
        for (; j + 4 <= cnt; j += 4) {
            int   sj0 = __builtin_amdgcn_readlane(s, j);
            int   sj1 = __builtin_amdgcn_readlane(s, j + 1);
            int   sj2 = __builtin_amdgcn_readlane(s, j + 2);
            int   sj3 = __builtin_amdgcn_readlane(s, j + 3);
            float p0 = readlane_f(w0, j),     q0 = readlane_f(w1, j);
            float p1 = readlane_f(w0, j + 1), q1 = readlane_f(w1, j + 1);
            float p2 = readlane_f(w0, j + 2), q2 = readlane_f(w1, j + 2);
            float p3 = readlane_f(w0, j + 3), q3 = readlane_f(w1, j + 3);
            unsigned u0 = hpk[(size_t)sj0 * 64 + lane];
            unsigned u1 = hpk[(size_t)sj1 * 64 + lane];
            unsigned u2 = hpk[(size_t)sj2 * 64 + lane];
            unsigned u3 = hpk[(size_t)sj3 * 64 + lane];
            acc0 = fmaf(p0, bf_lo(u0), acc0); acc1 = fmaf(q0, bf_hi(u0), acc1);
            acc0 = fmaf(p1, bf_lo(u1), acc0); acc1 = fmaf(q1, bf_hi(u1), acc1);
            acc0 = fmaf(p2, bf_lo(u2), acc0); acc1 = fmaf(q2, bf_hi(u2), acc1);
            acc0 = fmaf(p3, bf_lo(u3), acc0); acc1 = fmaf(q3, bf_hi(u3), acc1);
        }
        for (; j < cnt; ++j) {
            int   sj = __builtin_amdgcn_readlane(s, j);
            float p = readlane_f(w0, j), q = readlane_f(w1, j);
            unsigned u = hpk[(size_t)sj * 64 + lane];
            acc0 = fmaf(p, bf_lo(u), acc0);
            acc1 = fmaf(q, bf_hi(u), acc1);
        }
    }
    float o0 = acc0 / (sum0 + 1e-16f) + bias[lane];
    float o1 = acc1 / (sum1 + 1e-16f) + bias[64 + lane];
    out[(size_t)node * 128 + lane] = fmaxf(o0, 0.f);
    out[(size_t)node * 128 + 64 + lane] = fmaxf(o1, 0.f);
}

// ---------------------------------------------------------------- agg layer2: no-max, bf16 gather, no relu
__global__ void agg_layer2(const unsigned short* __restrict__ hb, const float* __restrict__ asrc,
                           const float* __restrict__ adst, const int* __restrict__ offs,
                           const int* __restrict__ csr, const float* __restrict__ bias,
                           float* __restrict__ out, int N) {
    int node = (blockIdx.x * blockDim.x + threadIdx.x) >> 6;
    int lane = threadIdx.x & 63;
    if (node >= N) return;
    int off = offs[node], end = offs[node + 1];
    float ad = adst[node];
    float wself = __expf(fminf(LEAKY(asrc[node] + ad), 60.f));
    float sum = wself;
    float acc = wself * __uint_as_float((unsigned)hb[(size_t)node * 64 + lane] << 16);

    for (int chunk = off; chunk < end; chunk += 64) {
        int e = chunk + lane;
        int s = 0;
        float w = 0.f;
        if (e < end) {
            s = csr[e];
            w = __expf(fminf(LEAKY(asrc[s] + ad), 60.f));
        }
        float t = w;
#pragma unroll
        for (int o = 32; o > 0; o >>= 1) t += __shfl_xor(t, o);
        sum += t;

        int cnt = min(64, end - chunk);
        int j = 0;
        for (; j + 4 <= cnt; j += 4) {
            int   sj0 = __builtin_amdgcn_readlane(s, j);
            int   sj1 = __builtin_amdgcn_readlane(s, j + 1);
            int   sj2 = __builtin_amdgcn_readlane(s, j + 2);
            int   sj3 = __builtin_amdgcn_readlane(s, j + 3);
            float p0 = readlane_f(w, j);
            float p1 = readlane_f(w, j + 1);
            float p2 = readlane_f(w, j + 2);
            float p3 = readlane_f(w, j + 3);
            float v0 = __uint_as_float((unsigned)hb[(size_t)sj0 * 64 + lane] << 16);
            float v1 = __uint_as_float((unsigned)hb[(size_t)sj1 * 64 + lane] << 16);
            float v2 = __uint_as_float((unsigned)hb[(size_t)sj2 * 64 + lane] << 16);
            float v3 = __uint_as_float((unsigned)hb[(size_t)sj3 * 64 + lane] << 16);
            acc = fmaf(p0, v0, acc);
            acc = fmaf(p1, v1, acc);
            acc = fmaf(p2, v2, acc);
            acc = fmaf(p3, v3, acc);
        }
        for (; j < cnt; ++j) {
            int   sj = __builtin_amdgcn_readlane(s, j);
            float p = readlane_f(w, j);
            acc = fmaf(p, __uint_as_float((unsigned)hb[(size_t)sj * 64 + lane] << 16), acc);
        }
    }
    out[(size_t)node * 64 + lane] = acc / (sum + 1e-16f) + bias[lane];
}

// ---------------------------------------------------------------- host
extern "C" void kernel_launch(void* const* d_in, const int* in_sizes, int n_in,
                              void* d_out, int out_size, void* d_ws, size_t ws_size,
                              hipStream_t stream) {
    const float* x        = (const float*)d_in[0];
    const int* ei         = (const int*)d_in[1];
    const float* W1       = (const float*)d_in[2];
    const float* att_src1 = (const float*)d_in[3];
    const float* att_dst1 = (const float*)d_in[4];
    const float* bias1    = (const float*)d_in[5];
    const float* W2       = (const float*)d_in[6];
    const float* att_src2 = (const float*)d_in[7];
    const float* att_dst2 = (const float*)d_in[8];
    const float* bias2    = (const float*)d_in[9];

    const int N = in_sizes[0] / 128;  // 100000
    const int E = in_sizes[1] / 2;    // 1600000

    char* base = (char*)d_ws;
    size_t off = 0;
    auto alloc = [&](size_t bytes) {
        char* p = base + off;
        off = (off + bytes + 255) & ~(size_t)255;
        return p;
    };
    int*      bcnt    = (int*)alloc((size_t)NBUCK * BPAD * 4);
    int*      bcur    = (int*)alloc((size_t)NBUCK * BPAD * 4);
    int*      bstart  = (int*)alloc((size_t)(NBUCK + 1) * 4);
    int*      offsets = (int*)alloc((size_t)(N + 1) * 4);
    int*      csr     = (int*)alloc((size_t)E * 4);
    int2*     ebuf    = (int2*)alloc((size_t)E * 8);
    unsigned* hpk     = (unsigned*)alloc((size_t)N * 64 * 4);       // packed bf16 pairs L1
    unsigned short* hb = (unsigned short*)alloc((size_t)N * 64 * 2); // bf16 L2
    float*    out1    = (float*)alloc((size_t)N * 128 * 4);          // L1 output (gemm2 input)
    float*    asrc1   = (float*)alloc((size_t)N * 2 * 4);
    float*    adst1   = (float*)alloc((size_t)N * 2 * 4);
    float*    asrc2   = (float*)alloc((size_t)N * 4);
    float*    adst2   = (float*)alloc((size_t)N * 4);

    const int mblocks = (N + 63) / 64;
    const int nwave_blocks = (N + 3) / 4;
    const int histBlocks = (E + 4095) / 4096;        // 391
    const int p1Blocks = (E + 4095) / 4096;          // 391
    const int nbuckets = (N + (1 << BSH) - 1) >> BSH; // 98

    // --- CSR prefix ---
    hipMemsetAsync(bcnt, 0, (size_t)NBUCK * BPAD * 4, stream);
    hist_bucket<<<histBlocks, 256, 0, stream>>>(ei, E, bcnt, histBlocks);
    scan_bucket<<<1, 64, 0, stream>>>(bcnt, bcur, bstart, offsets, N);

    // --- K1: layer1 GEMM+epilogue || pass1 edge binning ---
    fused_gemm1_pass1<<<p1Blocks + mblocks * 2, 256, 0, stream>>>(
        x, W1, N, att_src1, att_dst1, (unsigned short*)hpk, asrc1, adst1,
        ei, E, bcur, ebuf, p1Blocks, mblocks);

    // --- K2: per-bucket offsets + localized scatter ---
    pass2_build<<<nbuckets, 256, 0, stream>>>(ebuf, bstart, offsets, csr, N);

    // --- layer 1 aggregate ---
    agg_layer1<<<nwave_blocks, 256, 0, stream>>>(hpk, asrc1, adst1, offsets, csr, bias1, out1, N);

    // --- K3: layer2 GEMM+epilogue ---
    gemm2_epi<<<mblocks, 256, 0, stream>>>(out1, W2, N, att_src2, att_dst2, hb, asrc2, adst2);

    // --- layer 2 aggregate ---
    agg_layer2<<<nwave_blocks, 256, 0, stream>>>(hb, asrc2, adst2, offsets, csr, bias2,
                                                 (float*)d_out, N);
}

// Round 12
// 239.560 us; speedup vs baseline: 3.2625x; 1.2174x over previous
//
#include <hip/hip_runtime.h>
#include <hip/hip_bf16.h>
#include <cstdint>
#include <cstddef>

#define LEAKY(x) ((x) > 0.f ? (x) : 0.2f * (x))

#define NBUCK 128          // buckets of 1024 nodes (N=100000 -> 98 used)
#define BSH   10           // bucket shift
#define BPAD  16           // pad counters one 64B line apart
#define WPAD  136          // LDS W row pad (272B stride -> near-conflict-free frag reads)

typedef float        f32x4  __attribute__((ext_vector_type(4)));
typedef unsigned int u32x4  __attribute__((ext_vector_type(4)));
typedef short        bf16x8 __attribute__((ext_vector_type(8)));

__device__ __forceinline__ float readlane_f(float v, int l) {
    return __int_as_float(__builtin_amdgcn_readlane(__float_as_int(v), l));
}
// round-to-nearest-even fp32 -> bf16 bits
__device__ __forceinline__ unsigned short f2bf(float f) {
    unsigned x = __float_as_uint(f);
    return (unsigned short)((x + 0x7fffu + ((x >> 16) & 1u)) >> 16);
}
__device__ __forceinline__ float bf_lo(unsigned u) { return __uint_as_float(u << 16); }
__device__ __forceinline__ float bf_hi(unsigned u) { return __uint_as_float(u & 0xffff0000u); }

__device__ __forceinline__ bf16x8 as_bf16x8(u32x4 u) {
    union { u32x4 u4; bf16x8 b; } cv;
    cv.u4 = u;
    return cv.b;
}

// ---------------------------------------------------------------- bucket histogram
__global__ void hist_bucket(const int* __restrict__ ei, int E, int* __restrict__ bcnt,
                            int nblocks) {
    __shared__ int bl[NBUCK];
    for (int i = threadIdx.x; i < NBUCK; i += 256) bl[i] = 0;
    __syncthreads();
    const int stride = nblocks * 256;
    for (int e = blockIdx.x * 256 + threadIdx.x; e < E; e += stride)
        atomicAdd(&bl[ei[E + e] >> BSH], 1);
    __syncthreads();
    for (int i = threadIdx.x; i < NBUCK; i += 256) {
        int c = bl[i];
        if (c) atomicAdd(&bcnt[i * BPAD], c);
    }
}

// bucket exclusive scan (tiny)
__global__ void scan_bucket(const int* __restrict__ bcnt, int* __restrict__ bcur,
                            int* __restrict__ bstart, int* __restrict__ offsets, int n) {
    if (threadIdx.x == 0 && blockIdx.x == 0) {
        int run = 0;
        for (int b = 0; b < NBUCK; ++b) {
            int v = bcnt[b * BPAD];
            bcur[b * BPAD] = run;
            bstart[b] = run;
            run += v;
        }
        bstart[NBUCK] = run;
        offsets[n] = run;
    }
}

// ---------------------------------------------------------------- K1: pass1 (edge binning) || MFMA GEMM1 + epilogue
__global__ __launch_bounds__(256) void fused_gemm1_pass1(
    const float* __restrict__ x, const float* __restrict__ W1, int M,
    const float* __restrict__ att_src, const float* __restrict__ att_dst,
    unsigned* __restrict__ hpk, float* __restrict__ asrc, float* __restrict__ adst,
    const int* __restrict__ ei, int E, int* __restrict__ bcur, int2* __restrict__ ebuf,
    int p1Blocks) {
    const int tid = threadIdx.x;
    if ((int)blockIdx.x < p1Blocks) {
        __shared__ int bcnt_l[NBUCK];
        __shared__ int bbase_l[NBUCK];
        const int e0 = (int)blockIdx.x * 4096;
        const int ecnt = min(4096, E - e0);
        for (int i = tid; i < NBUCK; i += 256) bcnt_l[i] = 0;
        __syncthreads();
        for (int i = tid; i < ecnt; i += 256)
            atomicAdd(&bcnt_l[ei[E + e0 + i] >> BSH], 1);
        __syncthreads();
        if (tid < NBUCK) {
            int c = bcnt_l[tid];
            bbase_l[tid] = c ? atomicAdd(&bcur[tid * BPAD], c) : 0;
            bcnt_l[tid] = 0;
        }
        __syncthreads();
        for (int i = tid; i < ecnt; i += 256) {
            int s = ei[e0 + i];
            int d = ei[E + e0 + i];
            int b = d >> BSH;
            int l = atomicAdd(&bcnt_l[b], 1);
            ebuf[bbase_l[b] + l] = make_int2(s, d);
        }
    } else {
        __shared__ unsigned short Wt[128][WPAD];   // [col][k], bf16
        for (int i = tid; i < 128 * 128; i += 256) {
            int k = i >> 7, c = i & 127;
            Wt[c][k] = f2bf(W1[i]);
        }
        __syncthreads();
        const int gb = (int)blockIdx.x - p1Blocks;
        const int lane = tid & 63;
        const int li = lane & 15, g = lane >> 4;
        const int row0 = gb * 64 + (tid >> 6) * 16;
        const int arow = min(row0 + li, M - 1);
        f32x4 acc[8];
#pragma unroll
        for (int ct = 0; ct < 8; ++ct) acc[ct] = (f32x4)(0.f);
        const float* ap = x + (size_t)arow * 128 + g * 8;
#pragma unroll
        for (int ks = 0; ks < 4; ++ks) {
            float4 a0 = *(const float4*)(ap + ks * 32);
            float4 a1 = *(const float4*)(ap + ks * 32 + 4);
            u32x4 af;
            af.x = (unsigned)f2bf(a0.x) | ((unsigned)f2bf(a0.y) << 16);
            af.y = (unsigned)f2bf(a0.z) | ((unsigned)f2bf(a0.w) << 16);
            af.z = (unsigned)f2bf(a1.x) | ((unsigned)f2bf(a1.y) << 16);
            af.w = (unsigned)f2bf(a1.z) | ((unsigned)f2bf(a1.w) << 16);
            bf16x8 av = as_bf16x8(af);
#pragma unroll
            for (int ct = 0; ct < 8; ++ct) {
                bf16x8 bv = *(const bf16x8*)&Wt[ct * 16 + li][ks * 32 + g * 8];
                acc[ct] = __builtin_amdgcn_mfma_f32_16x16x32_bf16(av, bv, acc[ct], 0, 0, 0);
            }
        }
        // epilogue: scores + bf16 pack. head0 = cols 0..63 (ct 0..3), head1 = 64..127.
        float asv[8], adv[8];
#pragma unroll
        for (int ct = 0; ct < 8; ++ct) {
            asv[ct] = att_src[ct * 16 + li];
            adv[ct] = att_dst[ct * 16 + li];
        }
#pragma unroll
        for (int reg = 0; reg < 4; ++reg) {
            int r = row0 + g * 4 + reg;
            float ps0 = 0.f, pd0 = 0.f, ps1 = 0.f, pd1 = 0.f;
#pragma unroll
            for (int ct = 0; ct < 4; ++ct) {
                ps0 = fmaf(acc[ct][reg], asv[ct], ps0);
                pd0 = fmaf(acc[ct][reg], adv[ct], pd0);
                ps1 = fmaf(acc[ct + 4][reg], asv[ct + 4], ps1);
                pd1 = fmaf(acc[ct + 4][reg], adv[ct + 4], pd1);
            }
#pragma unroll
            for (int m = 8; m > 0; m >>= 1) {
                ps0 += __shfl_xor(ps0, m);
                pd0 += __shfl_xor(pd0, m);
                ps1 += __shfl_xor(ps1, m);
                pd1 += __shfl_xor(pd1, m);
            }
            if (r < M) {
                if (li == 0) {
                    asrc[2 * r] = ps0; asrc[2 * r + 1] = ps1;
                    adst[2 * r] = pd0; adst[2 * r + 1] = pd1;
                }
#pragma unroll
                for (int ct = 0; ct < 4; ++ct)
                    hpk[(size_t)r * 64 + ct * 16 + li] =
                        (unsigned)f2bf(acc[ct][reg]) | ((unsigned)f2bf(acc[ct + 4][reg]) << 16);
            }
        }
    }
}

// ---------------------------------------------------------------- K2: per-bucket offsets + localized scatter
__global__ __launch_bounds__(256) void pass2_build(
    const int2* __restrict__ ebuf, const int* __restrict__ bstart, int* __restrict__ offsets,
    int* __restrict__ csr, int N) {
    __shared__ int lcur[1 << BSH];
    __shared__ int ssum[256];
    const int b = blockIdx.x;
    const int dbase = b << BSH;
    const int tid = threadIdx.x;
    for (int i = tid; i < (1 << BSH); i += 256) lcur[i] = 0;
    __syncthreads();
    const int es = bstart[b], ee = bstart[b + 1];
    for (int i = es + tid; i < ee; i += 256)
        atomicAdd(&lcur[ebuf[i].y - dbase], 1);
    __syncthreads();
    const int base_ = tid * 4;
    int v0 = lcur[base_], v1 = lcur[base_ + 1], v2 = lcur[base_ + 2], v3 = lcur[base_ + 3];
    ssum[tid] = v0 + v1 + v2 + v3;
    __syncthreads();
    for (int o = 1; o < 256; o <<= 1) {
        int add = (tid >= o) ? ssum[tid - o] : 0;
        __syncthreads();
        ssum[tid] += add;
        __syncthreads();
    }
    int excl = (tid ? ssum[tid - 1] : 0) + bstart[b];
    int c0 = excl, c1 = c0 + v0, c2 = c1 + v1, c3 = c2 + v2;
    lcur[base_] = c0; lcur[base_ + 1] = c1; lcur[base_ + 2] = c2; lcur[base_ + 3] = c3;
    int idx = dbase + base_;
    if (idx < N)     offsets[idx] = c0;
    if (idx + 1 < N) offsets[idx + 1] = c1;
    if (idx + 2 < N) offsets[idx + 2] = c2;
    if (idx + 3 < N) offsets[idx + 3] = c3;
    __syncthreads();
    for (int i = es + tid; i < ee; i += 256) {
        int2 p = ebuf[i];
        int pos = atomicAdd(&lcur[p.y - dbase], 1);
        csr[pos] = p.x;
    }
}

// ---------------------------------------------------------------- K3: MFMA GEMM2 + epilogue
__global__ __launch_bounds__(256) void gemm2_epi(
    const unsigned short* __restrict__ A, const float* __restrict__ W2, int M,
    const float* __restrict__ att_src, const float* __restrict__ att_dst,
    unsigned short* __restrict__ hb, float* __restrict__ asrc, float* __restrict__ adst) {
    __shared__ unsigned short Wt[64][WPAD];
    const int tid = threadIdx.x;
    for (int i = tid; i < 128 * 64; i += 256) {
        int k = i >> 6, c = i & 63;
        Wt[c][k] = f2bf(W2[i]);
    }
    __syncthreads();
    const int lane = tid & 63;
    const int li = lane & 15, g = lane >> 4;
    const int row0 = blockIdx.x * 64 + (tid >> 6) * 16;
    const int arow = min(row0 + li, M - 1);
    f32x4 acc[4];
#pragma unroll
    for (int ct = 0; ct < 4; ++ct) acc[ct] = (f32x4)(0.f);
    const unsigned short* ap = A + (size_t)arow * 128 + g * 8;
#pragma unroll
    for (int ks = 0; ks < 4; ++ks) {
        bf16x8 av = *(const bf16x8*)(ap + ks * 32);
#pragma unroll
        for (int ct = 0; ct < 4; ++ct) {
            bf16x8 bv = *(const bf16x8*)&Wt[ct * 16 + li][ks * 32 + g * 8];
            acc[ct] = __builtin_amdgcn_mfma_f32_16x16x32_bf16(av, bv, acc[ct], 0, 0, 0);
        }
    }
    float asv[4], adv[4];
#pragma unroll
    for (int ct = 0; ct < 4; ++ct) {
        asv[ct] = att_src[ct * 16 + li];
        adv[ct] = att_dst[ct * 16 + li];
    }
#pragma unroll
    for (int reg = 0; reg < 4; ++reg) {
        int r = row0 + g * 4 + reg;
        float ps = 0.f, pd = 0.f;
#pragma unroll
        for (int ct = 0; ct < 4; ++ct) {
            ps = fmaf(acc[ct][reg], asv[ct], ps);
            pd = fmaf(acc[ct][reg], adv[ct], pd);
        }
#pragma unroll
        for (int m = 8; m > 0; m >>= 1) {
            ps += __shfl_xor(ps, m);
            pd += __shfl_xor(pd, m);
        }
        if (r < M) {
            if (li == 0) { asrc[r] = ps; adst[r] = pd; }
#pragma unroll
            for (int ct = 0; ct < 4; ++ct)
                hb[(size_t)r * 64 + ct * 16 + li] = f2bf(acc[ct][reg]);
        }
    }
}

// ---------------------------------------------------------------- agg layer1: no-max softmax + aggregate, bf16 out
__global__ void agg_layer1(const unsigned* __restrict__ hpk, const float* __restrict__ asrc,
                           const float* __restrict__ adst, const int* __restrict__ offs,
                           const int* __restrict__ csr, const float* __restrict__ bias,
                           unsigned short* __restrict__ out1b, int N) {
    int node = (blockIdx.x * blockDim.x + threadIdx.x) >> 6;
    int lane = threadIdx.x & 63;
    if (node >= N) return;
    int off = offs[node], end = offs[node + 1];
    float ad0 = adst[2 * node], ad1 = adst[2 * node + 1];
    float ws0 = __expf(fminf(LEAKY(asrc[2 * node] + ad0), 60.f));
    float ws1 = __expf(fminf(LEAKY(asrc[2 * node + 1] + ad1), 60.f));
    float sum0 = ws0, sum1 = ws1;
    float acc0, acc1;
    {
        unsigned u = hpk[(size_t)node * 64 + lane];
        acc0 = ws0 * bf_lo(u);
        acc1 = ws1 * bf_hi(u);
    }
    for (int chunk = off; chunk < end; chunk += 64) {
        int e = chunk + lane;
        int s = 0;
        float w0 = 0.f, w1 = 0.f;
        if (e < end) {
            s = csr[e];
            float2 as = *(const float2*)&asrc[2 * s];
            w0 = __expf(fminf(LEAKY(as.x + ad0), 60.f));
            w1 = __expf(fminf(LEAKY(as.y + ad1), 60.f));
        }
        float t0 = w0, t1 = w1;
#pragma unroll
        for (int o = 32; o > 0; o >>= 1) {
            t0 += __shfl_xor(t0, o);
            t1 += __shfl_xor(t1, o);
        }
        sum0 += t0; sum1 += t1;

        int cnt = min(64, end - chunk);
        int j = 0;
        for (; j + 4 <= cnt; j += 4) {
            int   sj0 = __builtin_amdgcn_readlane(s, j);
            int   sj1 = __builtin_amdgcn_readlane(s, j + 1);
            int   sj2 = __builtin_amdgcn_readlane(s, j + 2);
            int   sj3 = __builtin_amdgcn_readlane(s, j + 3);
            float p0 = readlane_f(w0, j),     q0 = readlane_f(w1, j);
            float p1 = readlane_f(w0, j + 1), q1 = readlane_f(w1, j + 1);
            float p2 = readlane_f(w0, j + 2), q2 = readlane_f(w1, j + 2);
            float p3 = readlane_f(w0, j + 3), q3 = readlane_f(w1, j + 3);
            unsigned u0 = hpk[(size_t)sj0 * 64 + lane];
            unsigned u1 = hpk[(size_t)sj1 * 64 + lane];
            unsigned u2 = hpk[(size_t)sj2 * 64 + lane];
            unsigned u3 = hpk[(size_t)sj3 * 64 + lane];
            acc0 = fmaf(p0, bf_lo(u0), acc0); acc1 = fmaf(q0, bf_hi(u0), acc1);
            acc0 = fmaf(p1, bf_lo(u1), acc0); acc1 = fmaf(q1, bf_hi(u1), acc1);
            acc0 = fmaf(p2, bf_lo(u2), acc0); acc1 = fmaf(q2, bf_hi(u2), acc1);
            acc0 = fmaf(p3, bf_lo(u3), acc0); acc1 = fmaf(q3, bf_hi(u3), acc1);
        }
        for (; j < cnt; ++j) {
            int   sj = __builtin_amdgcn_readlane(s, j);
            float p = readlane_f(w0, j), q = readlane_f(w1, j);
            unsigned u = hpk[(size_t)sj * 64 + lane];
            acc0 = fmaf(p, bf_lo(u), acc0);
            acc1 = fmaf(q, bf_hi(u), acc1);
        }
    }
    float o0 = acc0 / (sum0 + 1e-16f) + bias[lane];
    float o1 = acc1 / (sum1 + 1e-16f) + bias[64 + lane];
    out1b[(size_t)node * 128 + lane]      = f2bf(fmaxf(o0, 0.f));
    out1b[(size_t)node * 128 + 64 + lane] = f2bf(fmaxf(o1, 0.f));
}

// ---------------------------------------------------------------- agg layer2: no-max, bf16 gather, no relu
__global__ void agg_layer2(const unsigned short* __restrict__ hb, const float* __restrict__ asrc,
                           const float* __restrict__ adst, const int* __restrict__ offs,
                           const int* __restrict__ csr, const float* __restrict__ bias,
                           float* __restrict__ out, int N) {
    int node = (blockIdx.x * blockDim.x + threadIdx.x) >> 6;
    int lane = threadIdx.x & 63;
    if (node >= N) return;
    int off = offs[node], end = offs[node + 1];
    float ad = adst[node];
    float wself = __expf(fminf(LEAKY(asrc[node] + ad), 60.f));
    float sum = wself;
    float acc = wself * __uint_as_float((unsigned)hb[(size_t)node * 64 + lane] << 16);

    for (int chunk = off; chunk < end; chunk += 64) {
        int e = chunk + lane;
        int s = 0;
        float w = 0.f;
        if (e < end) {
            s = csr[e];
            w = __expf(fminf(LEAKY(asrc[s] + ad), 60.f));
        }
        float t = w;
#pragma unroll
        for (int o = 32; o > 0; o >>= 1) t += __shfl_xor(t, o);
        sum += t;

        int cnt = min(64, end - chunk);
        int j = 0;
        for (; j + 4 <= cnt; j += 4) {
            int   sj0 = __builtin_amdgcn_readlane(s, j);
            int   sj1 = __builtin_amdgcn_readlane(s, j + 1);
            int   sj2 = __builtin_amdgcn_readlane(s, j + 2);
            int   sj3 = __builtin_amdgcn_readlane(s, j + 3);
            float p0 = readlane_f(w, j);
            float p1 = readlane_f(w, j + 1);
            float p2 = readlane_f(w, j + 2);
            float p3 = readlane_f(w, j + 3);
            float v0 = __uint_as_float((unsigned)hb[(size_t)sj0 * 64 + lane] << 16);
            float v1 = __uint_as_float((unsigned)hb[(size_t)sj1 * 64 + lane] << 16);
            float v2 = __uint_as_float((unsigned)hb[(size_t)sj2 * 64 + lane] << 16);
            float v3 = __uint_as_float((unsigned)hb[(size_t)sj3 * 64 + lane] << 16);
            acc = fmaf(p0, v0, acc);
            acc = fmaf(p1, v1, acc);
            acc = fmaf(p2, v2, acc);
            acc = fmaf(p3, v3, acc);
        }
        for (; j < cnt; ++j) {
            int   sj = __builtin_amdgcn_readlane(s, j);
            float p = readlane_f(w, j);
            acc = fmaf(p, __uint_as_float((unsigned)hb[(size_t)sj * 64 + lane] << 16), acc);
        }
    }
    out[(size_t)node * 64 + lane] = acc / (sum + 1e-16f) + bias[lane];
}

// ---------------------------------------------------------------- host
extern "C" void kernel_launch(void* const* d_in, const int* in_sizes, int n_in,
                              void* d_out, int out_size, void* d_ws, size_t ws_size,
                              hipStream_t stream) {
    const float* x        = (const float*)d_in[0];
    const int* ei         = (const int*)d_in[1];
    const float* W1       = (const float*)d_in[2];
    const float* att_src1 = (const float*)d_in[3];
    const float* att_dst1 = (const float*)d_in[4];
    const float* bias1    = (const float*)d_in[5];
    const float* W2       = (const float*)d_in[6];
    const float* att_src2 = (const float*)d_in[7];
    const float* att_dst2 = (const float*)d_in[8];
    const float* bias2    = (const float*)d_in[9];

    const int N = in_sizes[0] / 128;  // 100000
    const int E = in_sizes[1] / 2;    // 1600000

    char* base = (char*)d_ws;
    size_t off = 0;
    auto alloc = [&](size_t bytes) {
        char* p = base + off;
        off = (off + bytes + 255) & ~(size_t)255;
        return p;
    };
    int*      bcnt    = (int*)alloc((size_t)NBUCK * BPAD * 4);
    int*      bcur    = (int*)alloc((size_t)NBUCK * BPAD * 4);
    int*      bstart  = (int*)alloc((size_t)(NBUCK + 1) * 4);
    int*      offsets = (int*)alloc((size_t)(N + 1) * 4);
    int*      csr     = (int*)alloc((size_t)E * 4);
    int2*     ebuf    = (int2*)alloc((size_t)E * 8);
    unsigned* hpk     = (unsigned*)alloc((size_t)N * 64 * 4);        // packed bf16 pairs L1
    unsigned short* hb    = (unsigned short*)alloc((size_t)N * 64 * 2);  // bf16 L2 features
    unsigned short* out1b = (unsigned short*)alloc((size_t)N * 128 * 2); // L1 output, bf16
    float*    asrc1   = (float*)alloc((size_t)N * 2 * 4);
    float*    adst1   = (float*)alloc((size_t)N * 2 * 4);
    float*    asrc2   = (float*)alloc((size_t)N * 4);
    float*    adst2   = (float*)alloc((size_t)N * 4);

    const int mblocks64 = (N + 63) / 64;              // 1563
    const int nwave_blocks = (N + 3) / 4;
    const int histBlocks = (E + 4095) / 4096;         // 391
    const int p1Blocks = (E + 4095) / 4096;           // 391
    const int nbuckets = (N + (1 << BSH) - 1) >> BSH; // 98

    // --- CSR prefix ---
    hipMemsetAsync(bcnt, 0, (size_t)NBUCK * BPAD * 4, stream);
    hist_bucket<<<histBlocks, 256, 0, stream>>>(ei, E, bcnt, histBlocks);
    scan_bucket<<<1, 64, 0, stream>>>(bcnt, bcur, bstart, offsets, N);

    // --- K1: MFMA GEMM1+epilogue || pass1 edge binning ---
    fused_gemm1_pass1<<<p1Blocks + mblocks64, 256, 0, stream>>>(
        x, W1, N, att_src1, att_dst1, hpk, asrc1, adst1, ei, E, bcur, ebuf, p1Blocks);

    // --- K2: per-bucket offsets + localized scatter ---
    pass2_build<<<nbuckets, 256, 0, stream>>>(ebuf, bstart, offsets, csr, N);

    // --- layer 1 aggregate (writes bf16) ---
    agg_layer1<<<nwave_blocks, 256, 0, stream>>>(hpk, asrc1, adst1, offsets, csr, bias1, out1b, N);

    // --- K3: MFMA GEMM2+epilogue ---
    gemm2_epi<<<mblocks64, 256, 0, stream>>>(out1b, W2, N, att_src2, att_dst2, hb, asrc2, adst2);

    // --- layer 2 aggregate ---
    agg_layer2<<<nwave_blocks, 256, 0, stream>>>(hb, asrc2, adst2, offsets, csr, bias2,
                                                 (float*)d_out, N);
}